// Round 5
// baseline (8286.151 us; speedup 1.0000x reference)
//
#include <hip/hip_runtime.h>
#include <hip/hip_bf16.h>

// ============================================================================
// VisionBDHv2 forward, MI355X (gfx950). Round 12.
// R11: 6880us (LDS-bounce epilogues, ln_ykv/ln1 folded away). Top kernel now
// k_attn: 98us x24, SQ_LDS_BANK_CONFLICT 3.64M/dispatch, MfmaUtil 11.4%.
// R12: k_attn only (everything else identical to R11):
//   a) swizzled BK=32 core: slot ^= (row>>1)&3 (4 slots x 2-row bank period
//      -> 8 dword-groups, 8/bank = conflict-free). Linear gload_lds dest +
//      pre-swizzled global col (involution) + same XOR on ds_read.
//   b) 2-phase pipeline (T3-minimum: stage next BEFORE compute, single
//      drain-barrier per step AFTER compute) for scores AND PV.
//      Scores parity-1 lives in Pl[0:16K] (dead during scores); PV parity-1
//      lives in lds_a (dead during PV). LDS stays 77.8KB -> 2 blocks/CU kept.
// ============================================================================

typedef short bf16x8 __attribute__((ext_vector_type(8)));
typedef float f32x4 __attribute__((ext_vector_type(4)));
typedef unsigned short u16;

#define LN_EPS 1e-5f
#define SM_SCALE 0.044194173824159216f  /* 1/sqrt(512) */
#define TWO_PI 6.283185307179586f
#define MC 3136                          /* rows per chunk = 16*196 */

typedef __attribute__((address_space(3))) unsigned char* as3p;
typedef const __attribute__((address_space(1))) unsigned char* as1p;

__device__ __forceinline__ void gload16(const u16* g, u16* l) {
    __builtin_amdgcn_global_load_lds((as1p)(const void*)g, (as3p)(void*)l, 16, 0, 0);
}

__device__ __forceinline__ u16 f2bf(float f) {
    __hip_bfloat16 h = __float2bfloat16(f);
    return *reinterpret_cast<u16*>(&h);
}
__device__ __forceinline__ float bf2f(u16 u) {
    return __uint_as_float(((unsigned)u) << 16);
}

// ---------------------------------------------------------------------------
// block reductions (256 threads, 4 waves)
// ---------------------------------------------------------------------------
__device__ __forceinline__ float block_reduce_sum(float v, float* sm) {
    #pragma unroll
    for (int o = 32; o; o >>= 1) v += __shfl_xor(v, o);
    if ((threadIdx.x & 63) == 0) sm[threadIdx.x >> 6] = v;
    __syncthreads();
    float r = sm[0] + sm[1] + sm[2] + sm[3];
    __syncthreads();
    return r;
}

// ---------------------------------------------------------------------------
// GEMM core (R7 gemm_core64, verbatim): BK=64, swizzled, 128x128 tile,
// 4 waves (2x2). LDS [128][64] u16 per operand; physical slot s holds
// logical col-slot s^(row&7). C/D: elem i -> row (lane>>4)*4+i, col lane&15.
// ---------------------------------------------------------------------------
__device__ __forceinline__ void gemm_core64(const u16* __restrict__ A, int lda,
                                            const u16* __restrict__ Bt, int ldb,
                                            int ksteps, f32x4 acc[4][4],
                                            u16* lds_a, u16* lds_b) {
    const int tid = threadIdx.x;
    const int lane = tid & 63;
    const int wave = tid >> 6;
    const int wr = (wave >> 1) * 64;
    const int wc = (wave & 1) * 64;
    const int lr = lane & 15;
    const int lg = lane >> 4;            // logical k-slot base (0..3)
    const int rx = lr & 7;               // row&7 for this lane's fragment rows
    const int srow = tid >> 3;           // staging row within 32-row group
    const int gslot = (tid & 7) ^ (srow & 7);  // pre-swizzled global col slot
    const u16* ga = A + (long)srow * lda + gslot * 8;
    const u16* gb = Bt + (long)srow * ldb + gslot * 8;
    u16* la = lds_a + tid * 8;           // linear dest: row srow, slot tid&7
    u16* lb = lds_b + tid * 8;
    for (int k0 = 0; k0 < ksteps; ++k0) {
        __syncthreads();                 // prior iteration's reads done
        #pragma unroll
        for (int j = 0; j < 4; ++j) {    // 32-row groups (row&7 invariant)
            gload16(ga + (long)(j * 32) * lda, la + j * 2048);
            gload16(gb + (long)(j * 32) * ldb, lb + j * 2048);
        }
        ga += 64; gb += 64;
        __syncthreads();                 // drains vmcnt(0) before barrier
        bf16x8 af[2][4], bfr[2][4];
        #pragma unroll
        for (int kk = 0; kk < 2; ++kk) {
            const int ps = ((lg + kk * 4) ^ rx) * 8;   // physical elem offset
            #pragma unroll
            for (int m = 0; m < 4; m++)
                af[kk][m] = *(const bf16x8*)&lds_a[(wr + 16 * m + lr) * 64 + ps];
            #pragma unroll
            for (int n = 0; n < 4; n++)
                bfr[kk][n] = *(const bf16x8*)&lds_b[(wc + 16 * n + lr) * 64 + ps];
        }
        #pragma unroll
        for (int kk = 0; kk < 2; ++kk)
            #pragma unroll
            for (int m = 0; m < 4; m++)
                #pragma unroll
                for (int n = 0; n < 4; n++)
                    acc[m][n] = __builtin_amdgcn_mfma_f32_16x16x32_bf16(
                        af[kk][m], bfr[kk][n], acc[m][n], 0, 0, 0);
    }
}

// merged 32KB LDS: gemm uses [lds_a | lds_b]; epilogue reuses as one tile
// (TU u16[128][128] or TF f32[64][128]).
#define GEMM64_PROLOGUE                                 \
    __shared__ alignas(16) u16 lds_ab[2 * 128 * 64];    \
    u16* lds_a = lds_ab;                                \
    u16* lds_b = lds_ab + 128 * 64;                     \
    f32x4 acc[4][4];                                    \
    _Pragma("unroll")                                   \
    for (int m = 0; m < 4; m++)                         \
        _Pragma("unroll")                               \
        for (int n = 0; n < 4; n++)                     \
            acc[m][n] = (f32x4){0.f, 0.f, 0.f, 0.f};

#define EPI_VARS                                        \
    const int lane = threadIdx.x & 63;                  \
    const int wave = threadIdx.x >> 6;                  \
    const int ewr = (wave >> 1) * 64 + (lane >> 4) * 4; \
    const int ewc = (wave & 1) * 64 + (lane & 15);

// ---------------------------------------------------------------------------
// Swizzled BK=32 core, 2-phase double-buffered (k_attn scores only).
// LDS [128][32] u16 per operand per parity. Physical slot s holds logical
// s^((row>>1)&3): fragment reads spread over all 8 dword-groups (8/bank,
// conflict-free). Pipeline: stage k+1 into other parity BEFORE computing k;
// one drain-barrier per step after compute (T3-minimum recipe).
// ---------------------------------------------------------------------------
__device__ __forceinline__ void gemm_core_sw(const u16* __restrict__ A, int lda,
                                             const u16* __restrict__ Bt, int ldb,
                                             int ksteps /*even*/, f32x4 acc[4][4],
                                             u16* a0, u16* b0, u16* a1, u16* b1) {
    const int tid = threadIdx.x;
    const int lane = tid & 63;
    const int wave = tid >> 6;
    const int wr = (wave >> 1) * 64;
    const int wc = (wave & 1) * 64;
    const int lr = lane & 15;
    const int lg = lane >> 4;
    const int ps = (lg ^ ((lr >> 1) & 3)) * 8;   // swizzled slot offset (u16)
    const int srow = tid >> 2;
    const int gslot = (tid & 3) ^ ((srow >> 1) & 3);  // pre-swizzled global slot
    const u16* ga = A + (long)srow * lda + gslot * 8;
    const u16* gb = Bt + (long)srow * ldb + gslot * 8;
    const long ha = (long)64 * lda, hb = (long)64 * ldb;

#define SSTG(pa, pb, k)                                                      \
    { gload16(ga + (k) * 32, (pa) + tid * 8);                                \
      gload16(ga + ha + (k) * 32, (pa) + 2048 + tid * 8);                    \
      gload16(gb + (k) * 32, (pb) + tid * 8);                                \
      gload16(gb + hb + (k) * 32, (pb) + 2048 + tid * 8); }
#define SCMP(pa, pb)                                                         \
    { bf16x8 af[4], bfr[4];                                                  \
      _Pragma("unroll")                                                      \
      for (int m = 0; m < 4; m++)                                            \
          af[m] = *(const bf16x8*)&(pa)[(wr + 16 * m + lr) * 32 + ps];       \
      _Pragma("unroll")                                                      \
      for (int n = 0; n < 4; n++)                                            \
          bfr[n] = *(const bf16x8*)&(pb)[(wc + 16 * n + lr) * 32 + ps];      \
      _Pragma("unroll")                                                      \
      for (int m = 0; m < 4; m++)                                            \
          _Pragma("unroll")                                                  \
          for (int n = 0; n < 4; n++)                                        \
              acc[m][n] = __builtin_amdgcn_mfma_f32_16x16x32_bf16(           \
                  af[m], bfr[n], acc[m][n], 0, 0, 0); }

    SSTG(a0, b0, 0)
    for (int k0 = 0; k0 < ksteps; k0 += 2) {
        __syncthreads();                         // stage(k0) visible; p1 reuse safe
        if (k0 + 1 < ksteps) SSTG(a1, b1, k0 + 1)
        SCMP(a0, b0)
        __syncthreads();                         // stage(k0+1) visible; p0 reuse safe
        if (k0 + 2 < ksteps) SSTG(a0, b0, k0 + 2)
        if (k0 + 1 < ksteps) SCMP(a1, b1)
    }
#undef SSTG
#undef SCMP
}

// ---------------------------------------------------------------------------
// setup kernels
// ---------------------------------------------------------------------------
__global__ __launch_bounds__(256) void k_pack_patches(const float* __restrict__ x,
                                                      u16* __restrict__ ap) {
    int idx = blockIdx.x * 256 + threadIdx.x;           // < 12544*768
    int r = idx / 768, k = idx - r * 768;
    int b = r / 196, t = r - b * 196;
    int hp = t / 14, wp = t - hp * 14;
    int c = k >> 8, rem = k & 255, p = rem >> 4, q = rem & 15;
    long src = ((long)(b * 3 + c) * 224 + hp * 16 + p) * 224 + wp * 16 + q;
    ap[idx] = f2bf(x[src]);
}

__global__ __launch_bounds__(256) void k_cast(const float* __restrict__ s,
                                              u16* __restrict__ d, int n) {
    int i = blockIdx.x * 256 + threadIdx.x;
    if (i < n) d[i] = f2bf(s[i]);
}

// src (batch, R, C) f32 -> dst (batch, C, R) bf16
__global__ __launch_bounds__(256) void k_transpose_cast(const float* __restrict__ src,
                                                        u16* __restrict__ dst,
                                                        int R, int C) {
    __shared__ float tile[32][33];
    int c0 = blockIdx.x * 32, r0 = blockIdx.y * 32;
    long base = (long)blockIdx.z * R * C;
    int i = threadIdx.x >> 5, j = threadIdx.x & 31;
    #pragma unroll
    for (int p = 0; p < 4; p++) {
        int rr = i + p * 8;
        tile[rr][j] = src[base + (long)(r0 + rr) * C + c0 + j];
    }
    __syncthreads();
    #pragma unroll
    for (int p = 0; p < 4; p++) {
        int rr = i + p * 8;
        dst[base + (long)(c0 + rr) * R + r0 + j] = f2bf(tile[j][rr]);
    }
}

__global__ __launch_bounds__(256) void k_rope_tab(const float* __restrict__ freqs,
                                                  float* __restrict__ tc,
                                                  float* __restrict__ ts) {
    int idx = blockIdx.x * 256 + threadIdx.x;           // < 196*512
    int t = idx >> 9, n = idx & 511;
    float ph = (float)t * freqs[n];
    ph = (ph - floorf(ph)) * TWO_PI;
    tc[idx] = cosf(ph);
    ts[idx] = sinf(ph);
}

// colsum[h][c] = sum_d encv[h][d][c]  (from f32 encv, coalesced in c)
__global__ __launch_bounds__(256) void k_colsum(const float* __restrict__ encv,
                                                float* __restrict__ cs) {
    int h = blockIdx.y, c = blockIdx.x * 256 + threadIdx.x;   // grid (2,12)
    const float* base = encv + (long)h * 768 * 512 + c;
    float a = 0.f;
    for (int d = 0; d < 768; d++) a += base[(long)d * 512];
    cs[h * 512 + c] = a;
}

// ---------------------------------------------------------------------------
// GEMM kernels (R7 core + LDS-bounce epilogues)
// ---------------------------------------------------------------------------
// tokens = patches @ convw^T + bias + pos_embed -> h   (M=12544,K=768,N=768)
__global__ __launch_bounds__(256) void k_gemm_tokens(const u16* __restrict__ ap,
                                                     const u16* __restrict__ bw,
                                                     const float* __restrict__ cb,
                                                     const float* __restrict__ pe,
                                                     float* __restrict__ hout) {
    GEMM64_PROLOGUE
    int row0 = blockIdx.x * 128, col0 = blockIdx.y * 128;
    gemm_core64(ap + (long)row0 * 768, 768, bw + (long)col0 * 768, 768, 12, acc, lds_a, lds_b);
    EPI_VARS
    const int tid = threadIdx.x;
    float* TF = (float*)lds_ab;          // [64][128] f32, two half-passes
    #pragma unroll
    for (int hf = 0; hf < 2; ++hf) {
        __syncthreads();
        if ((ewr >> 6) == hf) {
            #pragma unroll
            for (int m = 0; m < 4; m++)
                #pragma unroll
                for (int n = 0; n < 4; n++)
                    #pragma unroll
                    for (int i = 0; i < 4; i++) {
                        int row = row0 + ewr + 16 * m + i;
                        int col = col0 + ewc + 16 * n;
                        int t = row % 196;
                        TF[(ewr - hf * 64 + 16 * m + i) * 128 + ewc + 16 * n] =
                            acc[m][n][i] + cb[col] + pe[t * 768 + col];
                    }
        }
        __syncthreads();
        #pragma unroll
        for (int q = 0; q < 8; ++q) {
            int chunk = tid + q * 256;   // 64 rows x 32 chunks (16B=4 f32)
            int r = chunk >> 5, c = chunk & 31;
            *(f32x4*)&hout[(long)(row0 + hf * 64 + r) * 768 + col0 + c * 4] =
                *(f32x4*)&TF[r * 128 + c * 4];
        }
    }
}

// chunk: x_sparse = relu(hn@enc); qr = rope(x_sparse)  (M=3136 masked, N=6144)
// xs/qr written HEAD-MAJOR: [(head*16+bL)*196 + t][512]
__global__ __launch_bounds__(256) void k_gemm_xs(const u16* __restrict__ hnb,
                                                 const u16* __restrict__ enct,
                                                 const float* __restrict__ tc,
                                                 const float* __restrict__ tsn,
                                                 u16* __restrict__ xs,
                                                 u16* __restrict__ qr) {
    GEMM64_PROLOGUE
    // XCD swizzle: grid (25,48) -> 1200 wgs, q=150
    int p = blockIdx.x + 25 * blockIdx.y;
    int w = (p & 7) * 150 + (p >> 3);
    int row0 = (w % 25) * 128, col0 = (w / 25) * 128;
    int head = col0 >> 9, nn0 = col0 & 511;
    gemm_core64(hnb + (long)row0 * 768, 768,
                enct + ((long)head * 512 + nn0) * 768, 768, 12, acc, lds_a, lds_b);
    EPI_VARS
    const int tid = threadIdx.x;
    u16* TU = lds_ab;                    // [128][128] u16
    // ---- pass 1: xs = relu(acc) ----
    __syncthreads();
    #pragma unroll
    for (int m = 0; m < 4; m++)
        #pragma unroll
        for (int n = 0; n < 4; n++)
            #pragma unroll
            for (int i = 0; i < 4; i++)
                TU[(ewr + 16 * m + i) * 128 + ewc + 16 * n] =
                    f2bf(fmaxf(acc[m][n][i], 0.f));
    __syncthreads();
    #pragma unroll
    for (int q = 0; q < 8; ++q) {
        int chunk = tid + q * 256;       // 128 rows x 16 chunks (16B=8 u16)
        int r = chunk >> 4, c = chunk & 15;
        int row = row0 + r;
        if (row < MC)
            *(bf16x8*)&xs[((long)head * MC + row) * 512 + nn0 + c * 8] =
                *(bf16x8*)&TU[r * 128 + c * 8];
    }
    __syncthreads();
    // ---- pass 2: qr = rope(xs) ----
    #pragma unroll
    for (int m = 0; m < 4; m++)
        #pragma unroll
        for (int n = 0; n < 4; n++)
            #pragma unroll
            for (int i = 0; i < 4; i++) {
                int row = row0 + ewr + 16 * m + i;
                float v = fmaxf(acc[m][n][i], 0.f);
                float pp = __shfl_xor(v, 1);       // all lanes participate
                if (row < MC) {
                    int t = row % 196;
                    int nn = nn0 + ewc + 16 * n;
                    float cs = tc[t * 512 + nn], sn = tsn[t * 512 + nn];
                    float rot = (nn & 1) ? pp : -pp;
                    TU[(ewr + 16 * m + i) * 128 + ewc + 16 * n] =
                        f2bf(v * cs + rot * sn);
                }
            }
    __syncthreads();
    #pragma unroll
    for (int q = 0; q < 8; ++q) {
        int chunk = tid + q * 256;
        int r = chunk >> 4, c = chunk & 15;
        int row = row0 + r;
        if (row < MC)
            *(bf16x8*)&qr[((long)head * MC + row) * 512 + nn0 + c * 8] =
                *(bf16x8*)&TU[r * 128 + c * 8];
    }
}

// ---------------------------------------------------------------------------
// Fused attention + ykv row stats (mu, rs) for the ys LN-fold.
// R12: swizzled conflict-free BK=32 cores + 2-phase dbuf pipelines.
// Scores parity-1 = Pl[0:16K] (dead during scores); PV parity-1 = lds_a.
// ---------------------------------------------------------------------------
__global__ __launch_bounds__(256) void k_attn(const u16* __restrict__ qr,
                                              const u16* __restrict__ hnT,
                                              u16* __restrict__ ykv,
                                              float* __restrict__ stats) {
    __shared__ alignas(16) u16 lds_a[128 * 32];
    __shared__ alignas(16) u16 lds_b[128 * 32];
    __shared__ alignas(16) u16 Pl[128 * 232];   // [0:16K) = scores parity-1
    __shared__ float part[2][128][2];    // [max|sum][row][wave-col-half]
    const int tid = threadIdx.x, lane = tid & 63, wave = tid >> 6;
    const int wr = (wave >> 1) * 64, wc = (wave & 1) * 64;
    const int lr = lane & 15, lg = lane >> 4, lk = lg * 8;
    const int ps = (lg ^ ((lr >> 1) & 3)) * 8;   // swizzled slot (u16 units)
    const int row0 = blockIdx.x * 128, bh = blockIdx.y;  // bh = h*16+bL
    const int bL = bh & 15;
    const u16* qbase = qr + (long)bh * 196 * 512;
    u16* a1 = Pl;
    u16* b1 = Pl + 128 * 32;

    f32x4 acc0[4][4], acc1[4][4];
    #pragma unroll
    for (int m = 0; m < 4; m++)
        #pragma unroll
        for (int n = 0; n < 4; n++) {
            acc0[m][n] = (f32x4){0.f, 0.f, 0.f, 0.f};
            acc1[m][n] = (f32x4){0.f, 0.f, 0.f, 0.f};
        }
    // scores: S[row, col] = Q[row0+row] . Q[col], two 128-col tiles (K=512)
    gemm_core_sw(qbase + (long)row0 * 512, 512, qbase, 512, 16, acc0,
                 lds_a, lds_b, a1, b1);
    gemm_core_sw(qbase + (long)row0 * 512, 512, qbase + 128 * 512, 512, 16, acc1,
                 lds_a, lds_b, a1, b1);

    // ---- softmax over cols (valid < 196), scale applied inside exp ----
    const int rb = wr + (lane >> 4) * 4;
    #pragma unroll
    for (int m = 0; m < 4; m++)
        #pragma unroll
        for (int i = 0; i < 4; i++) {
            float mx = -1e30f;
            #pragma unroll
            for (int n = 0; n < 4; n++) {
                int c0 = wc + 16 * n + lr;
                if (c0 < 196) mx = fmaxf(mx, acc0[m][n][i]);
                if (c0 + 128 < 196) mx = fmaxf(mx, acc1[m][n][i]);
            }
            #pragma unroll
            for (int o = 1; o < 16; o <<= 1) mx = fmaxf(mx, __shfl_xor(mx, o));
            if (lr == 0) part[0][rb + 16 * m + i][wave & 1] = mx;
        }
    __syncthreads();      // also orders last scores reads of Pl-region before Pl writes
    #pragma unroll
    for (int m = 0; m < 4; m++)
        #pragma unroll
        for (int i = 0; i < 4; i++) {
            int row = rb + 16 * m + i;
            float rmx = fmaxf(part[0][row][0], part[0][row][1]);
            float s = 0.f;
            #pragma unroll
            for (int n = 0; n < 4; n++) {
                int c0 = wc + 16 * n + lr;
                float e0 = (c0 < 196) ? __expf((acc0[m][n][i] - rmx) * SM_SCALE) : 0.f;
                float e1 = (c0 + 128 < 196) ? __expf((acc1[m][n][i] - rmx) * SM_SCALE) : 0.f;
                acc0[m][n][i] = e0; acc1[m][n][i] = e1;
                s += e0 + e1;
            }
            #pragma unroll
            for (int o = 1; o < 16; o <<= 1) s += __shfl_xor(s, o);
            if (lr == 0) part[1][row][wave & 1] = s;
        }
    __syncthreads();
    #pragma unroll
    for (int m = 0; m < 4; m++)
        #pragma unroll
        for (int i = 0; i < 4; i++) {
            int row = rb + 16 * m + i;
            float inv = 1.f / (part[1][row][0] + part[1][row][1]);
            #pragma unroll
            for (int n = 0; n < 4; n++) {
                int c0 = wc + 16 * n + lr;
                Pl[row * 232 + c0] = f2bf(acc0[m][n][i] * inv);
                if (c0 + 128 < 224)
                    Pl[row * 232 + c0 + 128] = f2bf(acc1[m][n][i] * inv);
            }
        }
    // part[] now free: zero it for ykv row-stats accumulation
    __syncthreads();
    { float* pf = &part[0][0][0]; pf[tid] = 0.f; pf[tid + 256] = 0.f; }
    // ---- PV: O[row, d] = sum_s P[row,s] * hnT[d][s], 6 col-tiles, K=224 ----
    // 2-phase dbuf: parity0 = lds_b, parity1 = lds_a (dead during PV).
    const int srow = tid >> 2;
    const int gsl = (tid & 3) ^ ((srow >> 1) & 3);   // pre-swizzled global slot

#define PSTG(pb, Btp, k)                                                     \
    { gload16((Btp) + (long)srow * 224 + (k) * 32 + gsl * 8, (pb) + tid * 8); \
      gload16((Btp) + (long)(srow + 64) * 224 + (k) * 32 + gsl * 8,          \
              (pb) + 2048 + tid * 8); }
#define PCMP(pb, k)                                                          \
    { bf16x8 af[4], bfr[4];                                                  \
      _Pragma("unroll")                                                      \
      for (int m = 0; m < 4; m++)                                            \
          af[m] = *(const bf16x8*)&Pl[(wr + 16 * m + lr) * 232 + (k) * 32 + lk]; \
      _Pragma("unroll")                                                      \
      for (int n = 0; n < 4; n++)                                            \
          bfr[n] = *(const bf16x8*)&(pb)[(wc + 16 * n + lr) * 32 + ps];      \
      _Pragma("unroll")                                                      \
      for (int m = 0; m < 4; m++)                                            \
          _Pragma("unroll")                                                  \
          for (int n = 0; n < 4; n++)                                        \
              pacc[m][n] = __builtin_amdgcn_mfma_f32_16x16x32_bf16(          \
                  af[m], bfr[n], pacc[m][n], 0, 0, 0); }

    for (int cd = 0; cd < 6; ++cd) {
        const u16* Bt = hnT + ((long)bL * 768 + cd * 128) * 224;
        f32x4 pacc[4][4];
        #pragma unroll
        for (int m = 0; m < 4; m++)
            #pragma unroll
            for (int n = 0; n < 4; n++) pacc[m][n] = (f32x4){0.f, 0.f, 0.f, 0.f};
        PSTG(lds_b, Bt, 0)
        for (int k0 = 0; k0 < 7; k0 += 2) {
            __syncthreads();                     // stage(k0) visible
            if (k0 + 1 < 7) PSTG(lds_a, Bt, k0 + 1)
            PCMP(lds_b, k0)
            __syncthreads();                     // stage(k0+1) visible
            if (k0 + 2 < 7) PSTG(lds_b, Bt, k0 + 2)
            if (k0 + 1 < 7) PCMP(lds_a, k0 + 1)
        }
        // row-stats partials for this 128-col slab (per-thread slots, no race)
        #pragma unroll
        for (int m = 0; m < 4; m++)
            #pragma unroll
            for (int i = 0; i < 4; i++) {
                float s = pacc[m][0][i] + pacc[m][1][i] + pacc[m][2][i] + pacc[m][3][i];
                float q2 = pacc[m][0][i] * pacc[m][0][i] + pacc[m][1][i] * pacc[m][1][i] +
                           pacc[m][2][i] * pacc[m][2][i] + pacc[m][3][i] * pacc[m][3][i];
                #pragma unroll
                for (int o = 1; o < 16; o <<= 1) {
                    s += __shfl_xor(s, o);
                    q2 += __shfl_xor(q2, o);
                }
                if (lr == 0) {
                    part[0][rb + 16 * m + i][wave & 1] += s;
                    part[1][rb + 16 * m + i][wave & 1] += q2;
                }
            }
        EPI_VARS
        #pragma unroll
        for (int m = 0; m < 4; m++)
            #pragma unroll
            for (int n = 0; n < 4; n++)
                #pragma unroll
                for (int i = 0; i < 4; i++) {
                    int trow = row0 + ewr + 16 * m + i;
                    if (trow < 196)
                        ykv[((long)bh * 196 + trow) * 768 + cd * 128 + ewc + 16 * n] =
                            f2bf(pacc[m][n][i]);
                }
    }
#undef PSTG
#undef PCMP
    // finalize row stats
    __syncthreads();
    if (tid < 128) {
        int trow = row0 + tid;
        if (trow < 196) {
            float s = part[0][tid][0] + part[0][tid][1];
            float q2 = part[1][tid][0] + part[1][tid][1];
            float mu = s * (1.f / 768.f);
            float var = q2 * (1.f / 768.f) - mu * mu;
            float2 st;
            st.x = mu;
            st.y = rsqrtf(var + LN_EPS);
            *(float2*)&stats[((long)bh * 196 + trow) * 2] = st;
        }
    }
}

// y_sparse = relu(LN(ykv) @ encv) via fold: rs*(acc - mu*colsum);
// z = x_sparse*y_sparse, head-major flatten. grid (25,4,12), swizzled.
__global__ __launch_bounds__(256) void k_gemm_ys(const u16* __restrict__ ykv,
                                                 const u16* __restrict__ encvt,
                                                 const u16* __restrict__ xs,
                                                 const float* __restrict__ stats,
                                                 const float* __restrict__ colsum,
                                                 u16* __restrict__ z) {
    GEMM64_PROLOGUE
    // XCD swizzle: 1200 wgs, q=150
    int p = blockIdx.x + 25 * (blockIdx.y + 4 * blockIdx.z);
    int w = (p & 7) * 150 + (p >> 3);
    int rt = w % 25, rem = w / 25;
    int ct = rem & 3, h = rem >> 2;
    int row0 = rt * 128, col0 = ct * 128;
    gemm_core64(ykv + ((long)h * MC + row0) * 768, 768,
                encvt + ((long)h * 512 + col0) * 768, 768, 12, acc, lds_a, lds_b);
    EPI_VARS
    const int tid = threadIdx.x;
    u16* TU = lds_ab;                    // [128][128]
    // phase A: vector-load xs tile
    __syncthreads();
    #pragma unroll
    for (int q = 0; q < 8; ++q) {
        int chunk = tid + q * 256;
        int r = chunk >> 4, c = chunk & 15;
        *(bf16x8*)&TU[r * 128 + c * 8] =
            *(const bf16x8*)&xs[((long)h * MC + row0 + r) * 512 + col0 + c * 8];
    }
    __syncthreads();
    // phase B: in-place fold+relu+mul (thread-owned slots)
    #pragma unroll
    for (int m = 0; m < 4; m++)
        #pragma unroll
        for (int i = 0; i < 4; i++) {
            int rloc = ewr + 16 * m + i;
            int row = row0 + rloc;
            float mu = 0.f, rs = 0.f;
            if (row < MC) {
                float2 st = *(const float2*)&stats[((long)h * MC + row) * 2];
                mu = st.x; rs = st.y;
            }
            #pragma unroll
            for (int n = 0; n < 4; n++) {
                int cloc = ewc + 16 * n;
                float cs = colsum[h * 512 + col0 + cloc];
                float v = (acc[m][n][i] - mu * cs) * rs;
                v = fmaxf(v, 0.f) * bf2f(TU[rloc * 128 + cloc]);
                TU[rloc * 128 + cloc] = f2bf(v);
            }
        }
    __syncthreads();
    // phase C: vector-store z tile
    #pragma unroll
    for (int q = 0; q < 8; ++q) {
        int chunk = tid + q * 256;
        int r = chunk >> 4, c = chunk & 15;
        int row = row0 + r;
        if (row < MC)
            *(bf16x8*)&z[(long)row * 6144 + h * 512 + col0 + c * 8] =
                *(bf16x8*)&TU[r * 128 + c * 8];
    }
}

// yMLP_raw partial s = z[:, s*1536:(s+1)*1536] @ dec[s...]  (split-K4)
__global__ __launch_bounds__(256) void k_gemm_mlp(const u16* __restrict__ z,
                                                  const u16* __restrict__ dect,
                                                  float* __restrict__ rawK) {
    GEMM64_PROLOGUE
    // XCD swizzle: grid (25,6,4) -> 600 wgs, q=75
    int p = blockIdx.x + 25 * (blockIdx.y + 6 * blockIdx.z);
    int w = (p & 7) * 75 + (p >> 3);
    int row0 = (w % 25) * 128, col0 = ((w / 25) % 6) * 128, s = w / 150;
    gemm_core64(z + (long)row0 * 6144 + s * 1536, 6144,
                dect + (long)col0 * 6144 + s * 1536, 6144, 24, acc, lds_a, lds_b);
    EPI_VARS
    const int tid = threadIdx.x;
    float* TF = (float*)lds_ab;          // [64][128] f32, two half-passes
    float* raw = rawK + (long)s * MC * 768;
    #pragma unroll
    for (int hf = 0; hf < 2; ++hf) {
        __syncthreads();
        if ((ewr >> 6) == hf) {
            #pragma unroll
            for (int m = 0; m < 4; m++)
                #pragma unroll
                for (int n = 0; n < 4; n++)
                    #pragma unroll
                    for (int i = 0; i < 4; i++)
                        TF[(ewr - hf * 64 + 16 * m + i) * 128 + ewc + 16 * n] =
                            acc[m][n][i];
        }
        __syncthreads();
        #pragma unroll
        for (int q = 0; q < 8; ++q) {
            int chunk = tid + q * 256;
            int r = chunk >> 5, c = chunk & 31;
            int row = row0 + hf * 64 + r;
            if (row < MC)
                *(f32x4*)&raw[(long)row * 768 + col0 + c * 4] =
                    *(f32x4*)&TF[r * 128 + c * 4];
        }
    }
}

// ---------------------------------------------------------------------------
// per-row LN kernels
// ---------------------------------------------------------------------------
// hn = LN(h) -> hn bf16 (used ONCE after tokens; later layers skip: LN(LN)~id)
__global__ __launch_bounds__(256) void k_ln1(const float* __restrict__ h,
                                             u16* __restrict__ hnb) {
    __shared__ float sm[4];
    int r = blockIdx.x, tid = threadIdx.x;
    const float* p = h + (long)r * 768;
    float x0 = p[tid], x1 = p[tid + 256], x2 = p[tid + 512];
    float mean = block_reduce_sum(x0 + x1 + x2, sm) * (1.f / 768.f);
    float d0 = x0 - mean, d1 = x1 - mean, d2 = x2 - mean;
    float var = block_reduce_sum(d0 * d0 + d1 * d1 + d2 * d2, sm) * (1.f / 768.f);
    float rs = rsqrtf(var + LN_EPS);
    long ro = (long)r * 768;
    hnb[ro + tid] = f2bf(d0 * rs);
    hnb[ro + tid + 256] = f2bf(d1 * rs);
    hnb[ro + tid + 512] = f2bf(d2 * rs);
}

// hnT[b][d][tpad224] = hnb[b*196+t][d], t-pad zero-filled. 32x32 LDS tiles.
__global__ __launch_bounds__(256) void k_hnT(const u16* __restrict__ hnb,
                                             u16* __restrict__ hnT) {
    __shared__ u16 tile[32][33];
    int t0 = blockIdx.x * 32, d0 = blockIdx.y * 32, b = blockIdx.z;
    int i = threadIdx.x >> 5, j = threadIdx.x & 31;
    #pragma unroll
    for (int p = 0; p < 4; p++) {
        int t = t0 + i + p * 8;
        tile[i + p * 8][j] = (t < 196) ? hnb[((long)b * 196 + t) * 768 + d0 + j] : (u16)0;
    }
    __syncthreads();
    #pragma unroll
    for (int p = 0; p < 4; p++) {
        int dd = i + p * 8;
        hnT[((long)b * 768 + d0 + dd) * 224 + t0 + j] = tile[j][dd];
    }
}

// hnb = LN(hnb + LN(sum of 4 split-K partials))  [in-place: reads first]
__global__ __launch_bounds__(256) void k_final_h(const float* __restrict__ rawK,
                                                 u16* __restrict__ hnb) {
    __shared__ float sm[4];
    const long PS = (long)MC * 768;
    int r = blockIdx.x, tid = threadIdx.x;
    const float* rp = rawK + (long)r * 768;
    u16* hp = hnb + (long)r * 768;
    float y0 = rp[tid] + rp[tid + PS] + rp[tid + 2 * PS] + rp[tid + 3 * PS];
    float y1 = rp[tid + 256] + rp[tid + 256 + PS] + rp[tid + 256 + 2 * PS] + rp[tid + 256 + 3 * PS];
    float y2 = rp[tid + 512] + rp[tid + 512 + PS] + rp[tid + 512 + 2 * PS] + rp[tid + 512 + 3 * PS];
    float h0 = bf2f(hp[tid]), h1 = bf2f(hp[tid + 256]), h2 = bf2f(hp[tid + 512]);
    float mean = block_reduce_sum(y0 + y1 + y2, sm) * (1.f / 768.f);
    float d0 = y0 - mean, d1 = y1 - mean, d2 = y2 - mean;
    float var = block_reduce_sum(d0 * d0 + d1 * d1 + d2 * d2, sm) * (1.f / 768.f);
    float rs = rsqrtf(var + LN_EPS);
    float s0 = h0 + d0 * rs;
    float s1 = h1 + d1 * rs;
    float s2 = h2 + d2 * rs;
    mean = block_reduce_sum(s0 + s1 + s2, sm) * (1.f / 768.f);
    d0 = s0 - mean; d1 = s1 - mean; d2 = s2 - mean;
    var = block_reduce_sum(d0 * d0 + d1 * d1 + d2 * d2, sm) * (1.f / 768.f);
    rs = rsqrtf(var + LN_EPS);
    hp[tid] = f2bf(d0 * rs);
    hp[tid + 256] = f2bf(d1 * rs);
    hp[tid + 512] = f2bf(d2 * rs);
}

// pool stage 1: partial sums over 14-row groups -> part[b][g][768] (bf16 in)
__global__ __launch_bounds__(256) void k_pool1(const u16* __restrict__ hnb,
                                               float* __restrict__ part) {
    int g = blockIdx.x, b = blockIdx.y, tid = threadIdx.x;
    const u16* base = hnb + ((long)b * 196 + g * 14) * 768;
    float a0 = 0.f, a1 = 0.f, a2 = 0.f;
    for (int t = 0; t < 14; t++) {
        const u16* p = base + (long)t * 768;
        a0 += bf2f(p[tid]); a1 += bf2f(p[tid + 256]); a2 += bf2f(p[tid + 512]);
    }
    float* pp = part + ((long)b * 14 + g) * 768;
    pp[tid] = a0; pp[tid + 256] = a1; pp[tid + 512] = a2;
}

// pool stage 2: pooled = LN(sum(part)/196)
__global__ __launch_bounds__(256) void k_pool2(const float* __restrict__ part,
                                               float* __restrict__ pooled) {
    __shared__ float sm[4];
    int b = blockIdx.x, tid = threadIdx.x;
    const float* pp = part + (long)b * 14 * 768;
    float a0 = 0.f, a1 = 0.f, a2 = 0.f;
    for (int g = 0; g < 14; g++) {
        a0 += pp[g * 768 + tid]; a1 += pp[g * 768 + tid + 256]; a2 += pp[g * 768 + tid + 512];
    }
    a0 *= (1.f / 196.f); a1 *= (1.f / 196.f); a2 *= (1.f / 196.f);
    float mean = block_reduce_sum(a0 + a1 + a2, sm) * (1.f / 768.f);
    float d0 = a0 - mean, d1 = a1 - mean, d2 = a2 - mean;
    float var = block_reduce_sum(d0 * d0 + d1 * d1 + d2 * d2, sm) * (1.f / 768.f);
    float rs = rsqrtf(var + LN_EPS);
    pooled[(long)b * 768 + tid] = d0 * rs;
    pooled[(long)b * 768 + tid + 256] = d1 * rs;
    pooled[(long)b * 768 + tid + 512] = d2 * rs;
}

// out = pooled @ head_w^T + head_b.  grid (250, 64): wave w -> col 4*bx+w.
__global__ __launch_bounds__(256) void k_head(const float* __restrict__ pooled,
                                              const float* __restrict__ hw,
                                              const float* __restrict__ hb,
                                              float* __restrict__ out) {
    __shared__ float pr[768];
    int b = blockIdx.y, tid = threadIdx.x;
    pr[tid] = pooled[(long)b * 768 + tid];
    pr[tid + 256] = pooled[(long)b * 768 + tid + 256];
    pr[tid + 512] = pooled[(long)b * 768 + tid + 512];
    __syncthreads();
    int c = blockIdx.x * 4 + (tid >> 6);
    int lane = tid & 63;
    const float* wrow = hw + (long)c * 768;
    float acc = 0.f;
    #pragma unroll
    for (int k = 0; k < 768; k += 64) acc += pr[k + lane] * wrow[k + lane];
    #pragma unroll
    for (int o = 32; o; o >>= 1) acc += __shfl_xor(acc, o);
    if (lane == 0) out[(long)b * 1000 + c] = acc + hb[c];
}

// ---------------------------------------------------------------------------
extern "C" void kernel_launch(void* const* d_in, const int* in_sizes, int n_in,
                              void* d_out, int out_size, void* d_ws, size_t ws_size,
                              hipStream_t stream) {
    const float* x     = (const float*)d_in[0];
    const float* convw = (const float*)d_in[1];
    const float* convb = (const float*)d_in[2];
    const float* pe    = (const float*)d_in[3];
    const float* enc   = (const float*)d_in[4];
    const float* encv  = (const float*)d_in[5];
    const float* dec   = (const float*)d_in[6];
    const float* freqs = (const float*)d_in[7];
    const float* hw    = (const float*)d_in[8];
    const float* hbias = (const float*)d_in[9];
    float* out = (float*)d_out;

    char* W = (char*)d_ws;
    size_t off = 0;
    auto ALLOC = [&](size_t bytes) {
        size_t o = off;
        off += (bytes + 255) & ~(size_t)255;
        return o;
    };
    // persistent
    float* bh    = (float*)(W + ALLOC(38535168));            // h f32 (setup only)
    u16*   bhnb  = (u16*)  (W + ALLOC(19267584 + 524288));   // hn bf16 (+edge slack)
    u16*   bhnT  = (u16*)  (W + ALLOC(22020096));            // hn^T bf16 (64,768,224)
    u16*   benc  = (u16*)  (W + ALLOC(9437184));             // enc^T  (12,512,768)
    u16*   bencv = (u16*)  (W + ALLOC(9437184));             // encv^T
    u16*   bdec  = (u16*)  (W + ALLOC(9437184));             // dec^T  (768,6144)
    float* btc   = (float*)(W + ALLOC(401408));              // cos (196,512)
    float* bts   = (float*)(W + ALLOC(401408));              // sin
    float* bpool = (float*)(W + ALLOC(196608));              // pooled (64,768)
    float* bpart = (float*)(W + ALLOC(2752512));             // pool partials (64,14,768)
    float* bstats= (float*)(W + ALLOC(301056));              // ykv row stats (192*196 x f32x2)
    float* bcs   = (float*)(W + ALLOC(24576));               // encv colsums (12,512)
    // chunk regions (+slack for masked edge-tile overreads)
    char*  R1    = (char*) (W + ALLOC(38535168 + 2097152));  // qr / z
    char*  R2    = (char*) (W + ALLOC(57802752 + 524288));   // ykv / rawK (+setup patches)
    char*  R3    = (char*) (W + ALLOC(38535168 + 524288));   // xs (+setup conv_w)
    (void)ws_size; (void)in_sizes; (void)n_in; (void)out_size;

    u16*   bap  = (u16*)R2;    // setup: packed patches (18.4M)
    u16*   bcw  = (u16*)R3;    // setup: conv_w bf16 (1.2M)
    u16*   qr   = (u16*)R1;    // per-chunk head-major (192hb,196,512)
    u16*   z    = (u16*)R1;    // (3136,6144)
    u16*   ykv  = (u16*)R2;    // head-major (192hb,196,768)
    float* rawK = (float*)R2;  // yMLP split-K partials 4x(3136,768) f32
    u16*   xs   = (u16*)R3;    // head-major (192hb,196,512)

    // ---- setup ----
    k_pack_patches<<<37632, 256, 0, stream>>>(x, bap);
    k_cast<<<2304, 256, 0, stream>>>(convw, bcw, 768 * 768);
    k_gemm_tokens<<<dim3(98, 6), 256, 0, stream>>>(bap, bcw, convb, pe, bh);
    k_transpose_cast<<<dim3(16, 24, 12), 256, 0, stream>>>(enc, benc, 768, 512);
    k_transpose_cast<<<dim3(16, 24, 12), 256, 0, stream>>>(encv, bencv, 768, 512);
    k_transpose_cast<<<dim3(24, 192, 1), 256, 0, stream>>>(dec, bdec, 6144, 768);
    k_rope_tab<<<392, 256, 0, stream>>>(freqs, btc, bts);
    k_colsum<<<dim3(2, 12), 256, 0, stream>>>(encv, bcs);
    k_ln1<<<12544, 256, 0, stream>>>(bh, bhnb);   // once; thereafter LN(LN)~id

    // ---- 6 shared-weight layers, 4 chunks of 16 images each ----
    for (int L = 0; L < 6; ++L) {
        k_hnT<<<dim3(7, 24, 64), 256, 0, stream>>>(bhnb, bhnT);
        for (int c = 0; c < 4; ++c) {
            long r0 = (long)c * MC;                    // chunk row offset
            k_gemm_xs<<<dim3(25, 48), 256, 0, stream>>>(
                bhnb + r0 * 768, benc, btc, bts, xs, qr);
            k_attn<<<dim3(2, 192), 256, 0, stream>>>(
                qr, bhnT + (long)c * 16 * 768 * 224, ykv, bstats);
            k_gemm_ys<<<dim3(25, 4, 12), 256, 0, stream>>>(ykv, bencv, xs, bstats, bcs, z);
            k_gemm_mlp<<<dim3(25, 6, 4), 256, 0, stream>>>(z, bdec, rawK);
            k_final_h<<<MC, 256, 0, stream>>>(rawK, bhnb + r0 * 768);
        }
    }

    // ---- head ----
    k_pool1<<<dim3(14, 64), 256, 0, stream>>>(bhnb, bpart);
    k_pool2<<<64, 256, 0, stream>>>(bpart, bpool);
    k_head<<<dim3(250, 64), 256, 0, stream>>>(bpool, hw, hbias, out);
}

// Round 6
// 7614.538 us; speedup vs baseline: 1.0882x; 1.0882x over previous
//
#include <hip/hip_runtime.h>
#include <hip/hip_bf16.h>

// ============================================================================
// VisionBDHv2 forward, MI355X (gfx950). Round 13.
// R11: 6880us (proven). R12: 8286us REGRESSION - 2-phase pipeline around
// global_load_lds is impossible at HIP source level (compiler inserts
// conservative vmcnt waits before ds_reads when LDS-DMA is outstanding;
// confirmed 3x: R9/R10/R12). Swizzle itself WORKED (conflicts 3.64M->1.03M).
// R13 = R11 + new k_attn (serial stage->drain->compute kept, fewer steps):
//   - scores: merged col-tiles, BK=64: A staged ONCE, 8 drain-steps (was 32),
//     12 loads + 64 MFMA per step. B0/B1 overlay Pl[0:32K] (dead til pass-3).
//     core64 (row&7) swizzle (0-conflict proven).
//   - PV: cd-pairs: 2 d-slabs per pass, shared P-frags, 21 steps (was 42),
//     4 loads + 32 MFMA per step. R12's (row>>1)&3 swizzle (verified).
//   - drain-steps/block 74 -> 29; LDS 77.8KB -> 2 blocks/CU TLP kept.
// ============================================================================

typedef short bf16x8 __attribute__((ext_vector_type(8)));
typedef float f32x4 __attribute__((ext_vector_type(4)));
typedef unsigned short u16;

#define LN_EPS 1e-5f
#define SM_SCALE 0.044194173824159216f  /* 1/sqrt(512) */
#define TWO_PI 6.283185307179586f
#define MC 3136                          /* rows per chunk = 16*196 */

typedef __attribute__((address_space(3))) unsigned char* as3p;
typedef const __attribute__((address_space(1))) unsigned char* as1p;

__device__ __forceinline__ void gload16(const u16* g, u16* l) {
    __builtin_amdgcn_global_load_lds((as1p)(const void*)g, (as3p)(void*)l, 16, 0, 0);
}

__device__ __forceinline__ u16 f2bf(float f) {
    __hip_bfloat16 h = __float2bfloat16(f);
    return *reinterpret_cast<u16*>(&h);
}
__device__ __forceinline__ float bf2f(u16 u) {
    return __uint_as_float(((unsigned)u) << 16);
}

// ---------------------------------------------------------------------------
// block reductions (256 threads, 4 waves)
// ---------------------------------------------------------------------------
__device__ __forceinline__ float block_reduce_sum(float v, float* sm) {
    #pragma unroll
    for (int o = 32; o; o >>= 1) v += __shfl_xor(v, o);
    if ((threadIdx.x & 63) == 0) sm[threadIdx.x >> 6] = v;
    __syncthreads();
    float r = sm[0] + sm[1] + sm[2] + sm[3];
    __syncthreads();
    return r;
}

// ---------------------------------------------------------------------------
// GEMM core (R7 gemm_core64, verbatim): BK=64, swizzled, 128x128 tile,
// 4 waves (2x2). LDS [128][64] u16 per operand; physical slot s holds
// logical col-slot s^(row&7). C/D: elem i -> row (lane>>4)*4+i, col lane&15.
// ---------------------------------------------------------------------------
__device__ __forceinline__ void gemm_core64(const u16* __restrict__ A, int lda,
                                            const u16* __restrict__ Bt, int ldb,
                                            int ksteps, f32x4 acc[4][4],
                                            u16* lds_a, u16* lds_b) {
    const int tid = threadIdx.x;
    const int lane = tid & 63;
    const int wave = tid >> 6;
    const int wr = (wave >> 1) * 64;
    const int wc = (wave & 1) * 64;
    const int lr = lane & 15;
    const int lg = lane >> 4;            // logical k-slot base (0..3)
    const int rx = lr & 7;               // row&7 for this lane's fragment rows
    const int srow = tid >> 3;           // staging row within 32-row group
    const int gslot = (tid & 7) ^ (srow & 7);  // pre-swizzled global col slot
    const u16* ga = A + (long)srow * lda + gslot * 8;
    const u16* gb = Bt + (long)srow * ldb + gslot * 8;
    u16* la = lds_a + tid * 8;           // linear dest: row srow, slot tid&7
    u16* lb = lds_b + tid * 8;
    for (int k0 = 0; k0 < ksteps; ++k0) {
        __syncthreads();                 // prior iteration's reads done
        #pragma unroll
        for (int j = 0; j < 4; ++j) {    // 32-row groups (row&7 invariant)
            gload16(ga + (long)(j * 32) * lda, la + j * 2048);
            gload16(gb + (long)(j * 32) * ldb, lb + j * 2048);
        }
        ga += 64; gb += 64;
        __syncthreads();                 // drains vmcnt(0) before barrier
        bf16x8 af[2][4], bfr[2][4];
        #pragma unroll
        for (int kk = 0; kk < 2; ++kk) {
            const int ps = ((lg + kk * 4) ^ rx) * 8;   // physical elem offset
            #pragma unroll
            for (int m = 0; m < 4; m++)
                af[kk][m] = *(const bf16x8*)&lds_a[(wr + 16 * m + lr) * 64 + ps];
            #pragma unroll
            for (int n = 0; n < 4; n++)
                bfr[kk][n] = *(const bf16x8*)&lds_b[(wc + 16 * n + lr) * 64 + ps];
        }
        #pragma unroll
        for (int kk = 0; kk < 2; ++kk)
            #pragma unroll
            for (int m = 0; m < 4; m++)
                #pragma unroll
                for (int n = 0; n < 4; n++)
                    acc[m][n] = __builtin_amdgcn_mfma_f32_16x16x32_bf16(
                        af[kk][m], bfr[kk][n], acc[m][n], 0, 0, 0);
    }
}

// merged 32KB LDS: gemm uses [lds_a | lds_b]; epilogue reuses as one tile
// (TU u16[128][128] or TF f32[64][128]).
#define GEMM64_PROLOGUE                                 \
    __shared__ alignas(16) u16 lds_ab[2 * 128 * 64];    \
    u16* lds_a = lds_ab;                                \
    u16* lds_b = lds_ab + 128 * 64;                     \
    f32x4 acc[4][4];                                    \
    _Pragma("unroll")                                   \
    for (int m = 0; m < 4; m++)                         \
        _Pragma("unroll")                               \
        for (int n = 0; n < 4; n++)                     \
            acc[m][n] = (f32x4){0.f, 0.f, 0.f, 0.f};

#define EPI_VARS                                        \
    const int lane = threadIdx.x & 63;                  \
    const int wave = threadIdx.x >> 6;                  \
    const int ewr = (wave >> 1) * 64 + (lane >> 4) * 4; \
    const int ewc = (wave & 1) * 64 + (lane & 15);

// ---------------------------------------------------------------------------
// setup kernels
// ---------------------------------------------------------------------------
__global__ __launch_bounds__(256) void k_pack_patches(const float* __restrict__ x,
                                                      u16* __restrict__ ap) {
    int idx = blockIdx.x * 256 + threadIdx.x;           // < 12544*768
    int r = idx / 768, k = idx - r * 768;
    int b = r / 196, t = r - b * 196;
    int hp = t / 14, wp = t - hp * 14;
    int c = k >> 8, rem = k & 255, p = rem >> 4, q = rem & 15;
    long src = ((long)(b * 3 + c) * 224 + hp * 16 + p) * 224 + wp * 16 + q;
    ap[idx] = f2bf(x[src]);
}

__global__ __launch_bounds__(256) void k_cast(const float* __restrict__ s,
                                              u16* __restrict__ d, int n) {
    int i = blockIdx.x * 256 + threadIdx.x;
    if (i < n) d[i] = f2bf(s[i]);
}

// src (batch, R, C) f32 -> dst (batch, C, R) bf16
__global__ __launch_bounds__(256) void k_transpose_cast(const float* __restrict__ src,
                                                        u16* __restrict__ dst,
                                                        int R, int C) {
    __shared__ float tile[32][33];
    int c0 = blockIdx.x * 32, r0 = blockIdx.y * 32;
    long base = (long)blockIdx.z * R * C;
    int i = threadIdx.x >> 5, j = threadIdx.x & 31;
    #pragma unroll
    for (int p = 0; p < 4; p++) {
        int rr = i + p * 8;
        tile[rr][j] = src[base + (long)(r0 + rr) * C + c0 + j];
    }
    __syncthreads();
    #pragma unroll
    for (int p = 0; p < 4; p++) {
        int rr = i + p * 8;
        dst[base + (long)(c0 + rr) * R + r0 + j] = f2bf(tile[j][rr]);
    }
}

__global__ __launch_bounds__(256) void k_rope_tab(const float* __restrict__ freqs,
                                                  float* __restrict__ tc,
                                                  float* __restrict__ ts) {
    int idx = blockIdx.x * 256 + threadIdx.x;           // < 196*512
    int t = idx >> 9, n = idx & 511;
    float ph = (float)t * freqs[n];
    ph = (ph - floorf(ph)) * TWO_PI;
    tc[idx] = cosf(ph);
    ts[idx] = sinf(ph);
}

// colsum[h][c] = sum_d encv[h][d][c]  (from f32 encv, coalesced in c)
__global__ __launch_bounds__(256) void k_colsum(const float* __restrict__ encv,
                                                float* __restrict__ cs) {
    int h = blockIdx.y, c = blockIdx.x * 256 + threadIdx.x;   // grid (2,12)
    const float* base = encv + (long)h * 768 * 512 + c;
    float a = 0.f;
    for (int d = 0; d < 768; d++) a += base[(long)d * 512];
    cs[h * 512 + c] = a;
}

// ---------------------------------------------------------------------------
// GEMM kernels (R7 core + LDS-bounce epilogues)
// ---------------------------------------------------------------------------
// tokens = patches @ convw^T + bias + pos_embed -> h   (M=12544,K=768,N=768)
__global__ __launch_bounds__(256) void k_gemm_tokens(const u16* __restrict__ ap,
                                                     const u16* __restrict__ bw,
                                                     const float* __restrict__ cb,
                                                     const float* __restrict__ pe,
                                                     float* __restrict__ hout) {
    GEMM64_PROLOGUE
    int row0 = blockIdx.x * 128, col0 = blockIdx.y * 128;
    gemm_core64(ap + (long)row0 * 768, 768, bw + (long)col0 * 768, 768, 12, acc, lds_a, lds_b);
    EPI_VARS
    const int tid = threadIdx.x;
    float* TF = (float*)lds_ab;          // [64][128] f32, two half-passes
    #pragma unroll
    for (int hf = 0; hf < 2; ++hf) {
        __syncthreads();
        if ((ewr >> 6) == hf) {
            #pragma unroll
            for (int m = 0; m < 4; m++)
                #pragma unroll
                for (int n = 0; n < 4; n++)
                    #pragma unroll
                    for (int i = 0; i < 4; i++) {
                        int row = row0 + ewr + 16 * m + i;
                        int col = col0 + ewc + 16 * n;
                        int t = row % 196;
                        TF[(ewr - hf * 64 + 16 * m + i) * 128 + ewc + 16 * n] =
                            acc[m][n][i] + cb[col] + pe[t * 768 + col];
                    }
        }
        __syncthreads();
        #pragma unroll
        for (int q = 0; q < 8; ++q) {
            int chunk = tid + q * 256;   // 64 rows x 32 chunks (16B=4 f32)
            int r = chunk >> 5, c = chunk & 31;
            *(f32x4*)&hout[(long)(row0 + hf * 64 + r) * 768 + col0 + c * 4] =
                *(f32x4*)&TF[r * 128 + c * 4];
        }
    }
}

// chunk: x_sparse = relu(hn@enc); qr = rope(x_sparse)  (M=3136 masked, N=6144)
// xs/qr written HEAD-MAJOR: [(head*16+bL)*196 + t][512]
__global__ __launch_bounds__(256) void k_gemm_xs(const u16* __restrict__ hnb,
                                                 const u16* __restrict__ enct,
                                                 const float* __restrict__ tc,
                                                 const float* __restrict__ tsn,
                                                 u16* __restrict__ xs,
                                                 u16* __restrict__ qr) {
    GEMM64_PROLOGUE
    // XCD swizzle: grid (25,48) -> 1200 wgs, q=150
    int p = blockIdx.x + 25 * blockIdx.y;
    int w = (p & 7) * 150 + (p >> 3);
    int row0 = (w % 25) * 128, col0 = (w / 25) * 128;
    int head = col0 >> 9, nn0 = col0 & 511;
    gemm_core64(hnb + (long)row0 * 768, 768,
                enct + ((long)head * 512 + nn0) * 768, 768, 12, acc, lds_a, lds_b);
    EPI_VARS
    const int tid = threadIdx.x;
    u16* TU = lds_ab;                    // [128][128] u16
    // ---- pass 1: xs = relu(acc) ----
    __syncthreads();
    #pragma unroll
    for (int m = 0; m < 4; m++)
        #pragma unroll
        for (int n = 0; n < 4; n++)
            #pragma unroll
            for (int i = 0; i < 4; i++)
                TU[(ewr + 16 * m + i) * 128 + ewc + 16 * n] =
                    f2bf(fmaxf(acc[m][n][i], 0.f));
    __syncthreads();
    #pragma unroll
    for (int q = 0; q < 8; ++q) {
        int chunk = tid + q * 256;       // 128 rows x 16 chunks (16B=8 u16)
        int r = chunk >> 4, c = chunk & 15;
        int row = row0 + r;
        if (row < MC)
            *(bf16x8*)&xs[((long)head * MC + row) * 512 + nn0 + c * 8] =
                *(bf16x8*)&TU[r * 128 + c * 8];
    }
    __syncthreads();
    // ---- pass 2: qr = rope(xs) ----
    #pragma unroll
    for (int m = 0; m < 4; m++)
        #pragma unroll
        for (int n = 0; n < 4; n++)
            #pragma unroll
            for (int i = 0; i < 4; i++) {
                int row = row0 + ewr + 16 * m + i;
                float v = fmaxf(acc[m][n][i], 0.f);
                float pp = __shfl_xor(v, 1);       // all lanes participate
                if (row < MC) {
                    int t = row % 196;
                    int nn = nn0 + ewc + 16 * n;
                    float cs = tc[t * 512 + nn], sn = tsn[t * 512 + nn];
                    float rot = (nn & 1) ? pp : -pp;
                    TU[(ewr + 16 * m + i) * 128 + ewc + 16 * n] =
                        f2bf(v * cs + rot * sn);
                }
            }
    __syncthreads();
    #pragma unroll
    for (int q = 0; q < 8; ++q) {
        int chunk = tid + q * 256;
        int r = chunk >> 4, c = chunk & 15;
        int row = row0 + r;
        if (row < MC)
            *(bf16x8*)&qr[((long)head * MC + row) * 512 + nn0 + c * 8] =
                *(bf16x8*)&TU[r * 128 + c * 8];
    }
}

// ---------------------------------------------------------------------------
// Fused attention + ykv row stats (mu, rs) for the ys LN-fold.
// R13: serial stage->drain->compute (R11 structure) with merged loops:
//   scores BK=64 merged col-tiles (8 steps, A staged once);
//   PV cd-pairs (21 steps, shared P-frags). Swizzled staging throughout.
// LDS: ldsA 16KB (scores A / PV B0,B1); Pl 59KB ([0:32K) = scores B0,B1).
// ---------------------------------------------------------------------------
__global__ __launch_bounds__(256) void k_attn(const u16* __restrict__ qr,
                                              const u16* __restrict__ hnT,
                                              u16* __restrict__ ykv,
                                              float* __restrict__ stats) {
    __shared__ alignas(16) u16 ldsA[128 * 64];   // 16KB
    __shared__ alignas(16) u16 Pl[128 * 232];    // 59KB
    __shared__ float part[2][128][2];            // [max|sum][row][wave-col-half]
    const int tid = threadIdx.x, lane = tid & 63, wave = tid >> 6;
    const int wr = (wave >> 1) * 64, wc = (wave & 1) * 64;
    const int lr = lane & 15, lg = lane >> 4, lk = lg * 8;
    const int ewr = wr + lg * 4, ewc = wc + lr;  // C/D mapping
    const int row0 = blockIdx.x * 128, bh = blockIdx.y;  // bh = h*16+bL
    const int bL = bh & 15;
    const u16* qbase = qr + (long)bh * 196 * 512;
    u16* B0 = Pl;                 // scores B0 [128][64]
    u16* B1 = Pl + 128 * 64;      // scores B1 [128][64]

    f32x4 acc0[4][4], acc1[4][4];
    #pragma unroll
    for (int m = 0; m < 4; m++)
        #pragma unroll
        for (int n = 0; n < 4; n++) {
            acc0[m][n] = (f32x4){0.f, 0.f, 0.f, 0.f};
            acc1[m][n] = (f32x4){0.f, 0.f, 0.f, 0.f};
        }

    // ---- scores: S[r,c] = Q[row0+r].Q[c], cols 0..255 in one K-loop ----
    // BK=64, 8 steps; A staged once, B0 = Q rows 0..127, B1 = Q rows 128..255
    // (rows >=196 masked at softmax; overreads land in qr slack).
    {
        const int srow = tid >> 3;
        const int gsl = (tid & 7) ^ (srow & 7);
        const int rx = lr & 7;
        const u16* gA = qbase + (long)(row0 + srow) * 512 + gsl * 8;
        const u16* gB0 = qbase + (long)srow * 512 + gsl * 8;
        const u16* gB1 = qbase + (long)(128 + srow) * 512 + gsl * 8;
        for (int k0 = 0; k0 < 8; ++k0) {
            __syncthreads();             // prior step's reads done
            #pragma unroll
            for (int j = 0; j < 4; ++j) {
                gload16(gA + (long)(32 * j) * 512, ldsA + j * 2048 + tid * 8);
                gload16(gB0 + (long)(32 * j) * 512, B0 + j * 2048 + tid * 8);
                gload16(gB1 + (long)(32 * j) * 512, B1 + j * 2048 + tid * 8);
            }
            gA += 64; gB0 += 64; gB1 += 64;
            __syncthreads();             // drain vmcnt(0)
            #pragma unroll
            for (int kk = 0; kk < 2; ++kk) {
                const int ps = ((lg + 4 * kk) ^ rx) * 8;
                bf16x8 af[4], f0[4], f1[4];
                #pragma unroll
                for (int m = 0; m < 4; m++)
                    af[m] = *(const bf16x8*)&ldsA[(wr + 16 * m + lr) * 64 + ps];
                #pragma unroll
                for (int n = 0; n < 4; n++) {
                    f0[n] = *(const bf16x8*)&B0[(wc + 16 * n + lr) * 64 + ps];
                    f1[n] = *(const bf16x8*)&B1[(wc + 16 * n + lr) * 64 + ps];
                }
                #pragma unroll
                for (int m = 0; m < 4; m++)
                    #pragma unroll
                    for (int n = 0; n < 4; n++) {
                        acc0[m][n] = __builtin_amdgcn_mfma_f32_16x16x32_bf16(
                            af[m], f0[n], acc0[m][n], 0, 0, 0);
                        acc1[m][n] = __builtin_amdgcn_mfma_f32_16x16x32_bf16(
                            af[m], f1[n], acc1[m][n], 0, 0, 0);
                    }
            }
        }
    }

    // ---- softmax over cols (valid < 196), scale applied inside exp ----
    const int rb = wr + lg * 4;
    #pragma unroll
    for (int m = 0; m < 4; m++)
        #pragma unroll
        for (int i = 0; i < 4; i++) {
            float mx = -1e30f;
            #pragma unroll
            for (int n = 0; n < 4; n++) {
                int c0 = wc + 16 * n + lr;
                if (c0 < 196) mx = fmaxf(mx, acc0[m][n][i]);
                if (c0 + 128 < 196) mx = fmaxf(mx, acc1[m][n][i]);
            }
            #pragma unroll
            for (int o = 1; o < 16; o <<= 1) mx = fmaxf(mx, __shfl_xor(mx, o));
            if (lr == 0) part[0][rb + 16 * m + i][wave & 1] = mx;
        }
    __syncthreads();   // also orders last scores B0/B1 reads before Pl writes
    #pragma unroll
    for (int m = 0; m < 4; m++)
        #pragma unroll
        for (int i = 0; i < 4; i++) {
            int row = rb + 16 * m + i;
            float rmx = fmaxf(part[0][row][0], part[0][row][1]);
            float s = 0.f;
            #pragma unroll
            for (int n = 0; n < 4; n++) {
                int c0 = wc + 16 * n + lr;
                float e0 = (c0 < 196) ? __expf((acc0[m][n][i] - rmx) * SM_SCALE) : 0.f;
                float e1 = (c0 + 128 < 196) ? __expf((acc1[m][n][i] - rmx) * SM_SCALE) : 0.f;
                acc0[m][n][i] = e0; acc1[m][n][i] = e1;
                s += e0 + e1;
            }
            #pragma unroll
            for (int o = 1; o < 16; o <<= 1) s += __shfl_xor(s, o);
            if (lr == 0) part[1][row][wave & 1] = s;
        }
    __syncthreads();
    #pragma unroll
    for (int m = 0; m < 4; m++)
        #pragma unroll
        for (int i = 0; i < 4; i++) {
            int row = rb + 16 * m + i;
            float inv = 1.f / (part[1][row][0] + part[1][row][1]);
            #pragma unroll
            for (int n = 0; n < 4; n++) {
                int c0 = wc + 16 * n + lr;
                Pl[row * 232 + c0] = f2bf(acc0[m][n][i] * inv);
                if (c0 + 128 < 224)
                    Pl[row * 232 + c0 + 128] = f2bf(acc1[m][n][i] * inv);
            }
        }
    // part[] now free: zero it for ykv row-stats accumulation
    __syncthreads();
    { float* pf = &part[0][0][0]; pf[tid] = 0.f; pf[tid + 256] = 0.f; }

    // ---- PV: O[r,d] = sum_s P[r,s]*hnT[d][s]; 3 passes x 2 d-slabs ----
    // B0 -> ldsA[0:4096), B1 -> ldsA[4096:8192) (u16 units), K=224, 7 steps.
    {
        const int srow = tid >> 2;
        const int gsl = (tid & 3) ^ ((srow >> 1) & 3);
        const int ps = (lg ^ ((lr >> 1) & 3)) * 8;
        for (int cp = 0; cp < 3; ++cp) {
            const u16* Bt0 = hnT + ((long)bL * 768 + (2 * cp) * 128) * 224;
            const u16* Bt1 = Bt0 + 128 * 224;
            f32x4 p0[4][4], p1[4][4];
            #pragma unroll
            for (int m = 0; m < 4; m++)
                #pragma unroll
                for (int n = 0; n < 4; n++) {
                    p0[m][n] = (f32x4){0.f, 0.f, 0.f, 0.f};
                    p1[m][n] = (f32x4){0.f, 0.f, 0.f, 0.f};
                }
            for (int k0 = 0; k0 < 7; ++k0) {
                __syncthreads();
                gload16(Bt0 + (long)srow * 224 + k0 * 32 + gsl * 8, ldsA + tid * 8);
                gload16(Bt0 + (long)(srow + 64) * 224 + k0 * 32 + gsl * 8, ldsA + 2048 + tid * 8);
                gload16(Bt1 + (long)srow * 224 + k0 * 32 + gsl * 8, ldsA + 4096 + tid * 8);
                gload16(Bt1 + (long)(srow + 64) * 224 + k0 * 32 + gsl * 8, ldsA + 6144 + tid * 8);
                __syncthreads();
                bf16x8 af[4], f0[4], f1[4];
                #pragma unroll
                for (int m = 0; m < 4; m++)
                    af[m] = *(const bf16x8*)&Pl[(wr + 16 * m + lr) * 232 + k0 * 32 + lk];
                #pragma unroll
                for (int n = 0; n < 4; n++) {
                    f0[n] = *(const bf16x8*)&ldsA[(wc + 16 * n + lr) * 32 + ps];
                    f1[n] = *(const bf16x8*)&ldsA[4096 + (wc + 16 * n + lr) * 32 + ps];
                }
                #pragma unroll
                for (int m = 0; m < 4; m++)
                    #pragma unroll
                    for (int n = 0; n < 4; n++) {
                        p0[m][n] = __builtin_amdgcn_mfma_f32_16x16x32_bf16(
                            af[m], f0[n], p0[m][n], 0, 0, 0);
                        p1[m][n] = __builtin_amdgcn_mfma_f32_16x16x32_bf16(
                            af[m], f1[n], p1[m][n], 0, 0, 0);
                    }
            }
            // row-stats partials for both 128-col slabs (thread-owned slots)
            #pragma unroll
            for (int m = 0; m < 4; m++)
                #pragma unroll
                for (int i = 0; i < 4; i++) {
                    float s = p0[m][0][i] + p0[m][1][i] + p0[m][2][i] + p0[m][3][i]
                            + p1[m][0][i] + p1[m][1][i] + p1[m][2][i] + p1[m][3][i];
                    float q2 = p0[m][0][i] * p0[m][0][i] + p0[m][1][i] * p0[m][1][i]
                             + p0[m][2][i] * p0[m][2][i] + p0[m][3][i] * p0[m][3][i]
                             + p1[m][0][i] * p1[m][0][i] + p1[m][1][i] * p1[m][1][i]
                             + p1[m][2][i] * p1[m][2][i] + p1[m][3][i] * p1[m][3][i];
                    #pragma unroll
                    for (int o = 1; o < 16; o <<= 1) {
                        s += __shfl_xor(s, o);
                        q2 += __shfl_xor(q2, o);
                    }
                    if (lr == 0) {
                        part[0][rb + 16 * m + i][wave & 1] += s;
                        part[1][rb + 16 * m + i][wave & 1] += q2;
                    }
                }
            // epilogue: write both d-slabs
            #pragma unroll
            for (int m = 0; m < 4; m++)
                #pragma unroll
                for (int n = 0; n < 4; n++)
                    #pragma unroll
                    for (int i = 0; i < 4; i++) {
                        int trow = row0 + ewr + 16 * m + i;
                        if (trow < 196) {
                            long rbase = ((long)bh * 196 + trow) * 768;
                            ykv[rbase + (2 * cp) * 128 + ewc + 16 * n] = f2bf(p0[m][n][i]);
                            ykv[rbase + (2 * cp + 1) * 128 + ewc + 16 * n] = f2bf(p1[m][n][i]);
                        }
                    }
        }
    }
    // finalize row stats
    __syncthreads();
    if (tid < 128) {
        int trow = row0 + tid;
        if (trow < 196) {
            float s = part[0][tid][0] + part[0][tid][1];
            float q2 = part[1][tid][0] + part[1][tid][1];
            float mu = s * (1.f / 768.f);
            float var = q2 * (1.f / 768.f) - mu * mu;
            float2 st;
            st.x = mu;
            st.y = rsqrtf(var + LN_EPS);
            *(float2*)&stats[((long)bh * 196 + trow) * 2] = st;
        }
    }
}

// y_sparse = relu(LN(ykv) @ encv) via fold: rs*(acc - mu*colsum);
// z = x_sparse*y_sparse, head-major flatten. grid (25,4,12), swizzled.
__global__ __launch_bounds__(256) void k_gemm_ys(const u16* __restrict__ ykv,
                                                 const u16* __restrict__ encvt,
                                                 const u16* __restrict__ xs,
                                                 const float* __restrict__ stats,
                                                 const float* __restrict__ colsum,
                                                 u16* __restrict__ z) {
    GEMM64_PROLOGUE
    // XCD swizzle: 1200 wgs, q=150
    int p = blockIdx.x + 25 * (blockIdx.y + 4 * blockIdx.z);
    int w = (p & 7) * 150 + (p >> 3);
    int rt = w % 25, rem = w / 25;
    int ct = rem & 3, h = rem >> 2;
    int row0 = rt * 128, col0 = ct * 128;
    gemm_core64(ykv + ((long)h * MC + row0) * 768, 768,
                encvt + ((long)h * 512 + col0) * 768, 768, 12, acc, lds_a, lds_b);
    EPI_VARS
    const int tid = threadIdx.x;
    u16* TU = lds_ab;                    // [128][128]
    // phase A: vector-load xs tile
    __syncthreads();
    #pragma unroll
    for (int q = 0; q < 8; ++q) {
        int chunk = tid + q * 256;
        int r = chunk >> 4, c = chunk & 15;
        *(bf16x8*)&TU[r * 128 + c * 8] =
            *(const bf16x8*)&xs[((long)h * MC + row0 + r) * 512 + col0 + c * 8];
    }
    __syncthreads();
    // phase B: in-place fold+relu+mul (thread-owned slots)
    #pragma unroll
    for (int m = 0; m < 4; m++)
        #pragma unroll
        for (int i = 0; i < 4; i++) {
            int rloc = ewr + 16 * m + i;
            int row = row0 + rloc;
            float mu = 0.f, rs = 0.f;
            if (row < MC) {
                float2 st = *(const float2*)&stats[((long)h * MC + row) * 2];
                mu = st.x; rs = st.y;
            }
            #pragma unroll
            for (int n = 0; n < 4; n++) {
                int cloc = ewc + 16 * n;
                float cs = colsum[h * 512 + col0 + cloc];
                float v = (acc[m][n][i] - mu * cs) * rs;
                v = fmaxf(v, 0.f) * bf2f(TU[rloc * 128 + cloc]);
                TU[rloc * 128 + cloc] = f2bf(v);
            }
        }
    __syncthreads();
    // phase C: vector-store z tile
    #pragma unroll
    for (int q = 0; q < 8; ++q) {
        int chunk = tid + q * 256;
        int r = chunk >> 4, c = chunk & 15;
        int row = row0 + r;
        if (row < MC)
            *(bf16x8*)&z[(long)row * 6144 + h * 512 + col0 + c * 8] =
                *(bf16x8*)&TU[r * 128 + c * 8];
    }
}

// yMLP_raw partial s = z[:, s*1536:(s+1)*1536] @ dec[s...]  (split-K4)
__global__ __launch_bounds__(256) void k_gemm_mlp(const u16* __restrict__ z,
                                                  const u16* __restrict__ dect,
                                                  float* __restrict__ rawK) {
    GEMM64_PROLOGUE
    // XCD swizzle: grid (25,6,4) -> 600 wgs, q=75
    int p = blockIdx.x + 25 * (blockIdx.y + 6 * blockIdx.z);
    int w = (p & 7) * 75 + (p >> 3);
    int row0 = (w % 25) * 128, col0 = ((w / 25) % 6) * 128, s = w / 150;
    gemm_core64(z + (long)row0 * 6144 + s * 1536, 6144,
                dect + (long)col0 * 6144 + s * 1536, 6144, 24, acc, lds_a, lds_b);
    EPI_VARS
    const int tid = threadIdx.x;
    float* TF = (float*)lds_ab;          // [64][128] f32, two half-passes
    float* raw = rawK + (long)s * MC * 768;
    #pragma unroll
    for (int hf = 0; hf < 2; ++hf) {
        __syncthreads();
        if ((ewr >> 6) == hf) {
            #pragma unroll
            for (int m = 0; m < 4; m++)
                #pragma unroll
                for (int n = 0; n < 4; n++)
                    #pragma unroll
                    for (int i = 0; i < 4; i++)
                        TF[(ewr - hf * 64 + 16 * m + i) * 128 + ewc + 16 * n] =
                            acc[m][n][i];
        }
        __syncthreads();
        #pragma unroll
        for (int q = 0; q < 8; ++q) {
            int chunk = tid + q * 256;
            int r = chunk >> 5, c = chunk & 31;
            int row = row0 + hf * 64 + r;
            if (row < MC)
                *(f32x4*)&raw[(long)row * 768 + col0 + c * 4] =
                    *(f32x4*)&TF[r * 128 + c * 4];
        }
    }
}

// ---------------------------------------------------------------------------
// per-row LN kernels
// ---------------------------------------------------------------------------
// hn = LN(h) -> hn bf16 (used ONCE after tokens; later layers skip: LN(LN)~id)
__global__ __launch_bounds__(256) void k_ln1(const float* __restrict__ h,
                                             u16* __restrict__ hnb) {
    __shared__ float sm[4];
    int r = blockIdx.x, tid = threadIdx.x;
    const float* p = h + (long)r * 768;
    float x0 = p[tid], x1 = p[tid + 256], x2 = p[tid + 512];
    float mean = block_reduce_sum(x0 + x1 + x2, sm) * (1.f / 768.f);
    float d0 = x0 - mean, d1 = x1 - mean, d2 = x2 - mean;
    float var = block_reduce_sum(d0 * d0 + d1 * d1 + d2 * d2, sm) * (1.f / 768.f);
    float rs = rsqrtf(var + LN_EPS);
    long ro = (long)r * 768;
    hnb[ro + tid] = f2bf(d0 * rs);
    hnb[ro + tid + 256] = f2bf(d1 * rs);
    hnb[ro + tid + 512] = f2bf(d2 * rs);
}

// hnT[b][d][tpad224] = hnb[b*196+t][d], t-pad zero-filled. 32x32 LDS tiles.
__global__ __launch_bounds__(256) void k_hnT(const u16* __restrict__ hnb,
                                             u16* __restrict__ hnT) {
    __shared__ u16 tile[32][33];
    int t0 = blockIdx.x * 32, d0 = blockIdx.y * 32, b = blockIdx.z;
    int i = threadIdx.x >> 5, j = threadIdx.x & 31;
    #pragma unroll
    for (int p = 0; p < 4; p++) {
        int t = t0 + i + p * 8;
        tile[i + p * 8][j] = (t < 196) ? hnb[((long)b * 196 + t) * 768 + d0 + j] : (u16)0;
    }
    __syncthreads();
    #pragma unroll
    for (int p = 0; p < 4; p++) {
        int dd = i + p * 8;
        hnT[((long)b * 768 + d0 + dd) * 224 + t0 + j] = tile[j][dd];
    }
}

// hnb = LN(hnb + LN(sum of 4 split-K partials))  [in-place: reads first]
__global__ __launch_bounds__(256) void k_final_h(const float* __restrict__ rawK,
                                                 u16* __restrict__ hnb) {
    __shared__ float sm[4];
    const long PS = (long)MC * 768;
    int r = blockIdx.x, tid = threadIdx.x;
    const float* rp = rawK + (long)r * 768;
    u16* hp = hnb + (long)r * 768;
    float y0 = rp[tid] + rp[tid + PS] + rp[tid + 2 * PS] + rp[tid + 3 * PS];
    float y1 = rp[tid + 256] + rp[tid + 256 + PS] + rp[tid + 256 + 2 * PS] + rp[tid + 256 + 3 * PS];
    float y2 = rp[tid + 512] + rp[tid + 512 + PS] + rp[tid + 512 + 2 * PS] + rp[tid + 512 + 3 * PS];
    float h0 = bf2f(hp[tid]), h1 = bf2f(hp[tid + 256]), h2 = bf2f(hp[tid + 512]);
    float mean = block_reduce_sum(y0 + y1 + y2, sm) * (1.f / 768.f);
    float d0 = y0 - mean, d1 = y1 - mean, d2 = y2 - mean;
    float var = block_reduce_sum(d0 * d0 + d1 * d1 + d2 * d2, sm) * (1.f / 768.f);
    float rs = rsqrtf(var + LN_EPS);
    float s0 = h0 + d0 * rs;
    float s1 = h1 + d1 * rs;
    float s2 = h2 + d2 * rs;
    mean = block_reduce_sum(s0 + s1 + s2, sm) * (1.f / 768.f);
    d0 = s0 - mean; d1 = s1 - mean; d2 = s2 - mean;
    var = block_reduce_sum(d0 * d0 + d1 * d1 + d2 * d2, sm) * (1.f / 768.f);
    rs = rsqrtf(var + LN_EPS);
    hp[tid] = f2bf(d0 * rs);
    hp[tid + 256] = f2bf(d1 * rs);
    hp[tid + 512] = f2bf(d2 * rs);
}

// pool stage 1: partial sums over 14-row groups -> part[b][g][768] (bf16 in)
__global__ __launch_bounds__(256) void k_pool1(const u16* __restrict__ hnb,
                                               float* __restrict__ part) {
    int g = blockIdx.x, b = blockIdx.y, tid = threadIdx.x;
    const u16* base = hnb + ((long)b * 196 + g * 14) * 768;
    float a0 = 0.f, a1 = 0.f, a2 = 0.f;
    for (int t = 0; t < 14; t++) {
        const u16* p = base + (long)t * 768;
        a0 += bf2f(p[tid]); a1 += bf2f(p[tid + 256]); a2 += bf2f(p[tid + 512]);
    }
    float* pp = part + ((long)b * 14 + g) * 768;
    pp[tid] = a0; pp[tid + 256] = a1; pp[tid + 512] = a2;
}

// pool stage 2: pooled = LN(sum(part)/196)
__global__ __launch_bounds__(256) void k_pool2(const float* __restrict__ part,
                                               float* __restrict__ pooled) {
    __shared__ float sm[4];
    int b = blockIdx.x, tid = threadIdx.x;
    const float* pp = part + (long)b * 14 * 768;
    float a0 = 0.f, a1 = 0.f, a2 = 0.f;
    for (int g = 0; g < 14; g++) {
        a0 += pp[g * 768 + tid]; a1 += pp[g * 768 + tid + 256]; a2 += pp[g * 768 + tid + 512];
    }
    a0 *= (1.f / 196.f); a1 *= (1.f / 196.f); a2 *= (1.f / 196.f);
    float mean = block_reduce_sum(a0 + a1 + a2, sm) * (1.f / 768.f);
    float d0 = a0 - mean, d1 = a1 - mean, d2 = a2 - mean;
    float var = block_reduce_sum(d0 * d0 + d1 * d1 + d2 * d2, sm) * (1.f / 768.f);
    float rs = rsqrtf(var + LN_EPS);
    pooled[(long)b * 768 + tid] = d0 * rs;
    pooled[(long)b * 768 + tid + 256] = d1 * rs;
    pooled[(long)b * 768 + tid + 512] = d2 * rs;
}

// out = pooled @ head_w^T + head_b.  grid (250, 64): wave w -> col 4*bx+w.
__global__ __launch_bounds__(256) void k_head(const float* __restrict__ pooled,
                                              const float* __restrict__ hw,
                                              const float* __restrict__ hb,
                                              float* __restrict__ out) {
    __shared__ float pr[768];
    int b = blockIdx.y, tid = threadIdx.x;
    pr[tid] = pooled[(long)b * 768 + tid];
    pr[tid + 256] = pooled[(long)b * 768 + tid + 256];
    pr[tid + 512] = pooled[(long)b * 768 + tid + 512];
    __syncthreads();
    int c = blockIdx.x * 4 + (tid >> 6);
    int lane = tid & 63;
    const float* wrow = hw + (long)c * 768;
    float acc = 0.f;
    #pragma unroll
    for (int k = 0; k < 768; k += 64) acc += pr[k + lane] * wrow[k + lane];
    #pragma unroll
    for (int o = 32; o; o >>= 1) acc += __shfl_xor(acc, o);
    if (lane == 0) out[(long)b * 1000 + c] = acc + hb[c];
}

// ---------------------------------------------------------------------------
extern "C" void kernel_launch(void* const* d_in, const int* in_sizes, int n_in,
                              void* d_out, int out_size, void* d_ws, size_t ws_size,
                              hipStream_t stream) {
    const float* x     = (const float*)d_in[0];
    const float* convw = (const float*)d_in[1];
    const float* convb = (const float*)d_in[2];
    const float* pe    = (const float*)d_in[3];
    const float* enc   = (const float*)d_in[4];
    const float* encv  = (const float*)d_in[5];
    const float* dec   = (const float*)d_in[6];
    const float* freqs = (const float*)d_in[7];
    const float* hw    = (const float*)d_in[8];
    const float* hbias = (const float*)d_in[9];
    float* out = (float*)d_out;

    char* W = (char*)d_ws;
    size_t off = 0;
    auto ALLOC = [&](size_t bytes) {
        size_t o = off;
        off += (bytes + 255) & ~(size_t)255;
        return o;
    };
    // persistent
    float* bh    = (float*)(W + ALLOC(38535168));            // h f32 (setup only)
    u16*   bhnb  = (u16*)  (W + ALLOC(19267584 + 524288));   // hn bf16 (+edge slack)
    u16*   bhnT  = (u16*)  (W + ALLOC(22020096));            // hn^T bf16 (64,768,224)
    u16*   benc  = (u16*)  (W + ALLOC(9437184));             // enc^T  (12,512,768)
    u16*   bencv = (u16*)  (W + ALLOC(9437184));             // encv^T
    u16*   bdec  = (u16*)  (W + ALLOC(9437184));             // dec^T  (768,6144)
    float* btc   = (float*)(W + ALLOC(401408));              // cos (196,512)
    float* bts   = (float*)(W + ALLOC(401408));              // sin
    float* bpool = (float*)(W + ALLOC(196608));              // pooled (64,768)
    float* bpart = (float*)(W + ALLOC(2752512));             // pool partials (64,14,768)
    float* bstats= (float*)(W + ALLOC(301056));              // ykv row stats (192*196 x f32x2)
    float* bcs   = (float*)(W + ALLOC(24576));               // encv colsums (12,512)
    // chunk regions (+slack for masked edge-tile overreads)
    char*  R1    = (char*) (W + ALLOC(38535168 + 2097152));  // qr / z
    char*  R2    = (char*) (W + ALLOC(57802752 + 524288));   // ykv / rawK (+setup patches)
    char*  R3    = (char*) (W + ALLOC(38535168 + 524288));   // xs (+setup conv_w)
    (void)ws_size; (void)in_sizes; (void)n_in; (void)out_size;

    u16*   bap  = (u16*)R2;    // setup: packed patches (18.4M)
    u16*   bcw  = (u16*)R3;    // setup: conv_w bf16 (1.2M)
    u16*   qr   = (u16*)R1;    // per-chunk head-major (192hb,196,512)
    u16*   z    = (u16*)R1;    // (3136,6144)
    u16*   ykv  = (u16*)R2;    // head-major (192hb,196,768)
    float* rawK = (float*)R2;  // yMLP split-K partials 4x(3136,768) f32
    u16*   xs   = (u16*)R3;    // head-major (192hb,196,512)

    // ---- setup ----
    k_pack_patches<<<37632, 256, 0, stream>>>(x, bap);
    k_cast<<<2304, 256, 0, stream>>>(convw, bcw, 768 * 768);
    k_gemm_tokens<<<dim3(98, 6), 256, 0, stream>>>(bap, bcw, convb, pe, bh);
    k_transpose_cast<<<dim3(16, 24, 12), 256, 0, stream>>>(enc, benc, 768, 512);
    k_transpose_cast<<<dim3(16, 24, 12), 256, 0, stream>>>(encv, bencv, 768, 512);
    k_transpose_cast<<<dim3(24, 192, 1), 256, 0, stream>>>(dec, bdec, 6144, 768);
    k_rope_tab<<<392, 256, 0, stream>>>(freqs, btc, bts);
    k_colsum<<<dim3(2, 12), 256, 0, stream>>>(encv, bcs);
    k_ln1<<<12544, 256, 0, stream>>>(bh, bhnb);   // once; thereafter LN(LN)~id

    // ---- 6 shared-weight layers, 4 chunks of 16 images each ----
    for (int L = 0; L < 6; ++L) {
        k_hnT<<<dim3(7, 24, 64), 256, 0, stream>>>(bhnb, bhnT);
        for (int c = 0; c < 4; ++c) {
            long r0 = (long)c * MC;                    // chunk row offset
            k_gemm_xs<<<dim3(25, 48), 256, 0, stream>>>(
                bhnb + r0 * 768, benc, btc, bts, xs, qr);
            k_attn<<<dim3(2, 192), 256, 0, stream>>>(
                qr, bhnT + (long)c * 16 * 768 * 224, ykv, bstats);
            k_gemm_ys<<<dim3(25, 4, 12), 256, 0, stream>>>(ykv, bencv, xs, bstats, bcs, z);
            k_gemm_mlp<<<dim3(25, 6, 4), 256, 0, stream>>>(z, bdec, rawK);
            k_final_h<<<MC, 256, 0, stream>>>(rawK, bhnb + r0 * 768);
        }
    }

    // ---- head ----
    k_pool1<<<dim3(14, 64), 256, 0, stream>>>(bhnb, bpart);
    k_pool2<<<64, 256, 0, stream>>>(bpart, bpool);
    k_head<<<dim3(250, 64), 256, 0, stream>>>(bpool, hw, hbias, out);
}

// Round 7
// 7610.819 us; speedup vs baseline: 1.0887x; 1.0005x over previous
//
#include <hip/hip_runtime.h>
#include <hip/hip_bf16.h>

// ============================================================================
// VisionBDHv2 forward, MI355X (gfx950). Round 14.
// R11: 6880us (best). R12 (pipelined attn): 8286. R13 (fat-step attn): 7614.
// Lesson: serial THIN steps + max co-resident blocks wins; gload_lds forbids
// any source-level pipelining (compiler vmcnt legalizer, confirmed 3x).
// R14: T14 reg-staging everywhere (global_load->VGPR->ds_write):
//   - VGPR loads have real dep tracking -> tile-(k+1) loads issue BEFORE the
//     ds_read+MFMA phase; vmcnt wait lands at the post-MFMA barrier ->
//     latency hides under compute, compiler-legally.
//   - addressing byte-identical to proven layout: pre-swizzled global src +
//     LINEAR ds_write dest (tid*8 -> sequential dwords, conflict-free write)
//     + same XOR on ds_read.
//   - attn reverted to R11 structure; its BK=32 cores get reg-staging + the
//     R12-verified (row>>1)&3 read swizzle (conflict fix minus the pipeline).
// Everything else identical to R11/R13.
// ============================================================================

typedef short bf16x8 __attribute__((ext_vector_type(8)));
typedef float f32x4 __attribute__((ext_vector_type(4)));
typedef unsigned short u16;

#define LN_EPS 1e-5f
#define SM_SCALE 0.044194173824159216f  /* 1/sqrt(512) */
#define TWO_PI 6.283185307179586f
#define MC 3136                          /* rows per chunk = 16*196 */

__device__ __forceinline__ u16 f2bf(float f) {
    __hip_bfloat16 h = __float2bfloat16(f);
    return *reinterpret_cast<u16*>(&h);
}
__device__ __forceinline__ float bf2f(u16 u) {
    return __uint_as_float(((unsigned)u) << 16);
}

// ---------------------------------------------------------------------------
// block reductions (256 threads, 4 waves)
// ---------------------------------------------------------------------------
__device__ __forceinline__ float block_reduce_sum(float v, float* sm) {
    #pragma unroll
    for (int o = 32; o; o >>= 1) v += __shfl_xor(v, o);
    if ((threadIdx.x & 63) == 0) sm[threadIdx.x >> 6] = v;
    __syncthreads();
    float r = sm[0] + sm[1] + sm[2] + sm[3];
    __syncthreads();
    return r;
}

// ---------------------------------------------------------------------------
// GEMM core, reg-staged (T14): BK=64, 128x128 tile, 4 waves (2x2).
// Per step: issue 8 global_load_dwordx4 -> regs EARLY; ds_read frags + 32
// MFMA (latency hides here); barrier (drains vmcnt+lgkmcnt); ds_write regs
// to LINEAR dest (tid*8, sequential dwords = conflict-free); barrier.
// LDS [128][64] u16/operand; physical slot s holds logical s^(row&7) via
// pre-swizzled GLOBAL source col; ds_read applies same XOR.
// C/D: elem i -> row (lane>>4)*4+i, col lane&15.
// ---------------------------------------------------------------------------
__device__ __forceinline__ void gemm_core64(const u16* __restrict__ A, int lda,
                                            const u16* __restrict__ Bt, int ldb,
                                            int ksteps, f32x4 acc[4][4],
                                            u16* lds_a, u16* lds_b) {
    const int tid = threadIdx.x;
    const int lane = tid & 63;
    const int wave = tid >> 6;
    const int wr = (wave >> 1) * 64;
    const int wc = (wave & 1) * 64;
    const int lr = lane & 15;
    const int lg = lane >> 4;            // logical k-slot base (0..3)
    const int rx = lr & 7;               // row&7 for this lane's fragment rows
    const int srow = tid >> 3;           // staging row within 32-row group
    const int gslot = (tid & 7) ^ (srow & 7);  // pre-swizzled global col slot
    const u16* ga = A + (long)srow * lda + gslot * 8;
    const u16* gb = Bt + (long)srow * ldb + gslot * 8;
    u16* la = lds_a + tid * 8;           // linear dest: row srow, slot tid&7
    u16* lb = lds_b + tid * 8;
    bf16x8 ra[4], rb[4];
    // prologue: tile 0 -> regs -> LDS
    #pragma unroll
    for (int j = 0; j < 4; ++j) {
        ra[j] = *(const bf16x8*)(ga + (long)(j * 32) * lda);
        rb[j] = *(const bf16x8*)(gb + (long)(j * 32) * ldb);
    }
    ga += 64; gb += 64;
    #pragma unroll
    for (int j = 0; j < 4; ++j) {
        *(bf16x8*)(la + j * 2048) = ra[j];
        *(bf16x8*)(lb + j * 2048) = rb[j];
    }
    __syncthreads();
    for (int k0 = 0; k0 < ksteps; ++k0) {
        // issue next-tile loads early (latency hides under compute below)
        if (k0 + 1 < ksteps) {
            #pragma unroll
            for (int j = 0; j < 4; ++j) {
                ra[j] = *(const bf16x8*)(ga + (long)(j * 32) * lda);
                rb[j] = *(const bf16x8*)(gb + (long)(j * 32) * ldb);
            }
            ga += 64; gb += 64;
        }
        bf16x8 af[2][4], bfr[2][4];
        #pragma unroll
        for (int kk = 0; kk < 2; ++kk) {
            const int ps = ((lg + kk * 4) ^ rx) * 8;   // physical elem offset
            #pragma unroll
            for (int m = 0; m < 4; m++)
                af[kk][m] = *(const bf16x8*)&lds_a[(wr + 16 * m + lr) * 64 + ps];
            #pragma unroll
            for (int n = 0; n < 4; n++)
                bfr[kk][n] = *(const bf16x8*)&lds_b[(wc + 16 * n + lr) * 64 + ps];
        }
        #pragma unroll
        for (int kk = 0; kk < 2; ++kk)
            #pragma unroll
            for (int m = 0; m < 4; m++)
                #pragma unroll
                for (int n = 0; n < 4; n++)
                    acc[m][n] = __builtin_amdgcn_mfma_f32_16x16x32_bf16(
                        af[kk][m], bfr[kk][n], acc[m][n], 0, 0, 0);
        __syncthreads();                 // all LDS reads done (+vmcnt drain)
        if (k0 + 1 < ksteps) {
            #pragma unroll
            for (int j = 0; j < 4; ++j) {
                *(bf16x8*)(la + j * 2048) = ra[j];
                *(bf16x8*)(lb + j * 2048) = rb[j];
            }
        }
        __syncthreads();                 // writes visible
    }
}

// merged 32KB LDS: gemm uses [lds_a | lds_b]; epilogue reuses as one tile
// (TU u16[128][128] or TF f32[64][128]).
#define GEMM64_PROLOGUE                                 \
    __shared__ alignas(16) u16 lds_ab[2 * 128 * 64];    \
    u16* lds_a = lds_ab;                                \
    u16* lds_b = lds_ab + 128 * 64;                     \
    f32x4 acc[4][4];                                    \
    _Pragma("unroll")                                   \
    for (int m = 0; m < 4; m++)                         \
        _Pragma("unroll")                               \
        for (int n = 0; n < 4; n++)                     \
            acc[m][n] = (f32x4){0.f, 0.f, 0.f, 0.f};

#define EPI_VARS                                        \
    const int lane = threadIdx.x & 63;                  \
    const int wave = threadIdx.x >> 6;                  \
    const int ewr = (wave >> 1) * 64 + (lane >> 4) * 4; \
    const int ewc = (wave & 1) * 64 + (lane & 15);

// ---------------------------------------------------------------------------
// BK=32 reg-staged core (k_attn scores). Swizzled reads: physical slot s
// holds logical s^((row>>1)&3) (R12-verified conflict fix); pre-swizzled
// global source, linear ds_write dest.
// ---------------------------------------------------------------------------
__device__ __forceinline__ void gemm_core32r(const u16* __restrict__ A, int lda,
                                             const u16* __restrict__ Bt, int ldb,
                                             int ksteps, f32x4 acc[4][4],
                                             u16* lds_a, u16* lds_b) {
    const int tid = threadIdx.x;
    const int lane = tid & 63;
    const int wave = tid >> 6;
    const int wr = (wave >> 1) * 64;
    const int wc = (wave & 1) * 64;
    const int lr = lane & 15;
    const int lg = lane >> 4;
    const int ps = (lg ^ ((lr >> 1) & 3)) * 8;   // swizzled read slot (u16)
    const int srow = tid >> 2;                   // 0..63
    const int gslot = (tid & 3) ^ ((srow >> 1) & 3);  // pre-swizzled global
    const u16* ga = A + (long)srow * lda + gslot * 8;
    const u16* gb = Bt + (long)srow * ldb + gslot * 8;
    const long ha = (long)64 * lda, hb = (long)64 * ldb;
    u16* la = lds_a + tid * 8;
    u16* lb = lds_b + tid * 8;
    bf16x8 r0, r1, r2, r3;
    r0 = *(const bf16x8*)(ga); r1 = *(const bf16x8*)(ga + ha);
    r2 = *(const bf16x8*)(gb); r3 = *(const bf16x8*)(gb + hb);
    ga += 32; gb += 32;
    *(bf16x8*)la = r0; *(bf16x8*)(la + 2048) = r1;
    *(bf16x8*)lb = r2; *(bf16x8*)(lb + 2048) = r3;
    __syncthreads();
    for (int k0 = 0; k0 < ksteps; ++k0) {
        if (k0 + 1 < ksteps) {
            r0 = *(const bf16x8*)(ga); r1 = *(const bf16x8*)(ga + ha);
            r2 = *(const bf16x8*)(gb); r3 = *(const bf16x8*)(gb + hb);
            ga += 32; gb += 32;
        }
        bf16x8 af[4], bfr[4];
        #pragma unroll
        for (int m = 0; m < 4; m++)
            af[m] = *(const bf16x8*)&lds_a[(wr + 16 * m + lr) * 32 + ps];
        #pragma unroll
        for (int n = 0; n < 4; n++)
            bfr[n] = *(const bf16x8*)&lds_b[(wc + 16 * n + lr) * 32 + ps];
        #pragma unroll
        for (int m = 0; m < 4; m++)
            #pragma unroll
            for (int n = 0; n < 4; n++)
                acc[m][n] = __builtin_amdgcn_mfma_f32_16x16x32_bf16(
                    af[m], bfr[n], acc[m][n], 0, 0, 0);
        __syncthreads();
        if (k0 + 1 < ksteps) {
            *(bf16x8*)la = r0; *(bf16x8*)(la + 2048) = r1;
            *(bf16x8*)lb = r2; *(bf16x8*)(lb + 2048) = r3;
        }
        __syncthreads();
    }
}

// ---------------------------------------------------------------------------
// setup kernels
// ---------------------------------------------------------------------------
__global__ __launch_bounds__(256) void k_pack_patches(const float* __restrict__ x,
                                                      u16* __restrict__ ap) {
    int idx = blockIdx.x * 256 + threadIdx.x;           // < 12544*768
    int r = idx / 768, k = idx - r * 768;
    int b = r / 196, t = r - b * 196;
    int hp = t / 14, wp = t - hp * 14;
    int c = k >> 8, rem = k & 255, p = rem >> 4, q = rem & 15;
    long src = ((long)(b * 3 + c) * 224 + hp * 16 + p) * 224 + wp * 16 + q;
    ap[idx] = f2bf(x[src]);
}

__global__ __launch_bounds__(256) void k_cast(const float* __restrict__ s,
                                              u16* __restrict__ d, int n) {
    int i = blockIdx.x * 256 + threadIdx.x;
    if (i < n) d[i] = f2bf(s[i]);
}

// src (batch, R, C) f32 -> dst (batch, C, R) bf16
__global__ __launch_bounds__(256) void k_transpose_cast(const float* __restrict__ src,
                                                        u16* __restrict__ dst,
                                                        int R, int C) {
    __shared__ float tile[32][33];
    int c0 = blockIdx.x * 32, r0 = blockIdx.y * 32;
    long base = (long)blockIdx.z * R * C;
    int i = threadIdx.x >> 5, j = threadIdx.x & 31;
    #pragma unroll
    for (int p = 0; p < 4; p++) {
        int rr = i + p * 8;
        tile[rr][j] = src[base + (long)(r0 + rr) * C + c0 + j];
    }
    __syncthreads();
    #pragma unroll
    for (int p = 0; p < 4; p++) {
        int rr = i + p * 8;
        dst[base + (long)(c0 + rr) * R + r0 + j] = f2bf(tile[j][rr]);
    }
}

__global__ __launch_bounds__(256) void k_rope_tab(const float* __restrict__ freqs,
                                                  float* __restrict__ tc,
                                                  float* __restrict__ ts) {
    int idx = blockIdx.x * 256 + threadIdx.x;           // < 196*512
    int t = idx >> 9, n = idx & 511;
    float ph = (float)t * freqs[n];
    ph = (ph - floorf(ph)) * TWO_PI;
    tc[idx] = cosf(ph);
    ts[idx] = sinf(ph);
}

// colsum[h][c] = sum_d encv[h][d][c]  (from f32 encv, coalesced in c)
__global__ __launch_bounds__(256) void k_colsum(const float* __restrict__ encv,
                                                float* __restrict__ cs) {
    int h = blockIdx.y, c = blockIdx.x * 256 + threadIdx.x;   // grid (2,12)
    const float* base = encv + (long)h * 768 * 512 + c;
    float a = 0.f;
    for (int d = 0; d < 768; d++) a += base[(long)d * 512];
    cs[h * 512 + c] = a;
}

// ---------------------------------------------------------------------------
// GEMM kernels (reg-staged core + LDS-bounce epilogues)
// ---------------------------------------------------------------------------
// tokens = patches @ convw^T + bias + pos_embed -> h   (M=12544,K=768,N=768)
__global__ __launch_bounds__(256) void k_gemm_tokens(const u16* __restrict__ ap,
                                                     const u16* __restrict__ bw,
                                                     const float* __restrict__ cb,
                                                     const float* __restrict__ pe,
                                                     float* __restrict__ hout) {
    GEMM64_PROLOGUE
    int row0 = blockIdx.x * 128, col0 = blockIdx.y * 128;
    gemm_core64(ap + (long)row0 * 768, 768, bw + (long)col0 * 768, 768, 12, acc, lds_a, lds_b);
    EPI_VARS
    const int tid = threadIdx.x;
    float* TF = (float*)lds_ab;          // [64][128] f32, two half-passes
    #pragma unroll
    for (int hf = 0; hf < 2; ++hf) {
        __syncthreads();
        if ((ewr >> 6) == hf) {
            #pragma unroll
            for (int m = 0; m < 4; m++)
                #pragma unroll
                for (int n = 0; n < 4; n++)
                    #pragma unroll
                    for (int i = 0; i < 4; i++) {
                        int row = row0 + ewr + 16 * m + i;
                        int col = col0 + ewc + 16 * n;
                        int t = row % 196;
                        TF[(ewr - hf * 64 + 16 * m + i) * 128 + ewc + 16 * n] =
                            acc[m][n][i] + cb[col] + pe[t * 768 + col];
                    }
        }
        __syncthreads();
        #pragma unroll
        for (int q = 0; q < 8; ++q) {
            int chunk = tid + q * 256;   // 64 rows x 32 chunks (16B=4 f32)
            int r = chunk >> 5, c = chunk & 31;
            *(f32x4*)&hout[(long)(row0 + hf * 64 + r) * 768 + col0 + c * 4] =
                *(f32x4*)&TF[r * 128 + c * 4];
        }
    }
}

// chunk: x_sparse = relu(hn@enc); qr = rope(x_sparse)  (M=3136 masked, N=6144)
// xs/qr written HEAD-MAJOR: [(head*16+bL)*196 + t][512]
__global__ __launch_bounds__(256) void k_gemm_xs(const u16* __restrict__ hnb,
                                                 const u16* __restrict__ enct,
                                                 const float* __restrict__ tc,
                                                 const float* __restrict__ tsn,
                                                 u16* __restrict__ xs,
                                                 u16* __restrict__ qr) {
    GEMM64_PROLOGUE
    // XCD swizzle: grid (25,48) -> 1200 wgs, q=150
    int p = blockIdx.x + 25 * blockIdx.y;
    int w = (p & 7) * 150 + (p >> 3);
    int row0 = (w % 25) * 128, col0 = (w / 25) * 128;
    int head = col0 >> 9, nn0 = col0 & 511;
    gemm_core64(hnb + (long)row0 * 768, 768,
                enct + ((long)head * 512 + nn0) * 768, 768, 12, acc, lds_a, lds_b);
    EPI_VARS
    const int tid = threadIdx.x;
    u16* TU = lds_ab;                    // [128][128] u16
    // ---- pass 1: xs = relu(acc) ----
    __syncthreads();
    #pragma unroll
    for (int m = 0; m < 4; m++)
        #pragma unroll
        for (int n = 0; n < 4; n++)
            #pragma unroll
            for (int i = 0; i < 4; i++)
                TU[(ewr + 16 * m + i) * 128 + ewc + 16 * n] =
                    f2bf(fmaxf(acc[m][n][i], 0.f));
    __syncthreads();
    #pragma unroll
    for (int q = 0; q < 8; ++q) {
        int chunk = tid + q * 256;       // 128 rows x 16 chunks (16B=8 u16)
        int r = chunk >> 4, c = chunk & 15;
        int row = row0 + r;
        if (row < MC)
            *(bf16x8*)&xs[((long)head * MC + row) * 512 + nn0 + c * 8] =
                *(bf16x8*)&TU[r * 128 + c * 8];
    }
    __syncthreads();
    // ---- pass 2: qr = rope(xs) ----
    #pragma unroll
    for (int m = 0; m < 4; m++)
        #pragma unroll
        for (int n = 0; n < 4; n++)
            #pragma unroll
            for (int i = 0; i < 4; i++) {
                int row = row0 + ewr + 16 * m + i;
                float v = fmaxf(acc[m][n][i], 0.f);
                float pp = __shfl_xor(v, 1);       // all lanes participate
                if (row < MC) {
                    int t = row % 196;
                    int nn = nn0 + ewc + 16 * n;
                    float cs = tc[t * 512 + nn], sn = tsn[t * 512 + nn];
                    float rot = (nn & 1) ? pp : -pp;
                    TU[(ewr + 16 * m + i) * 128 + ewc + 16 * n] =
                        f2bf(v * cs + rot * sn);
                }
            }
    __syncthreads();
    #pragma unroll
    for (int q = 0; q < 8; ++q) {
        int chunk = tid + q * 256;
        int r = chunk >> 4, c = chunk & 15;
        int row = row0 + r;
        if (row < MC)
            *(bf16x8*)&qr[((long)head * MC + row) * 512 + nn0 + c * 8] =
                *(bf16x8*)&TU[r * 128 + c * 8];
    }
}

// ---------------------------------------------------------------------------
// Fused attention + ykv row stats (mu, rs) for the ys LN-fold.
// R11 structure (serial thin steps, 2 blocks/CU) with reg-staged swizzled
// cores: scores 2x gemm_core32r; PV 6 cd-passes, 7 steps each, reg-staged B.
// ---------------------------------------------------------------------------
__global__ __launch_bounds__(256) void k_attn(const u16* __restrict__ qr,
                                              const u16* __restrict__ hnT,
                                              u16* __restrict__ ykv,
                                              float* __restrict__ stats) {
    __shared__ alignas(16) u16 lds_a[128 * 32];
    __shared__ alignas(16) u16 lds_b[128 * 32];
    __shared__ alignas(16) u16 Pl[128 * 232];
    __shared__ float part[2][128][2];    // [max|sum][row][wave-col-half]
    const int tid = threadIdx.x, lane = tid & 63, wave = tid >> 6;
    const int wr = (wave >> 1) * 64, wc = (wave & 1) * 64;
    const int lr = lane & 15, lg = lane >> 4, lk = lg * 8;
    const int ps = (lg ^ ((lr >> 1) & 3)) * 8;   // swizzled read slot (u16)
    const int row0 = blockIdx.x * 128, bh = blockIdx.y;  // bh = h*16+bL
    const int bL = bh & 15;
    const u16* qbase = qr + (long)bh * 196 * 512;

    f32x4 acc0[4][4], acc1[4][4];
    #pragma unroll
    for (int m = 0; m < 4; m++)
        #pragma unroll
        for (int n = 0; n < 4; n++) {
            acc0[m][n] = (f32x4){0.f, 0.f, 0.f, 0.f};
            acc1[m][n] = (f32x4){0.f, 0.f, 0.f, 0.f};
        }
    // scores: S[row, col] = Q[row0+row] . Q[col], two 128-col tiles (K=512)
    gemm_core32r(qbase + (long)row0 * 512, 512, qbase, 512, 16, acc0, lds_a, lds_b);
    gemm_core32r(qbase + (long)row0 * 512, 512, qbase + 128 * 512, 512, 16, acc1, lds_a, lds_b);

    // ---- softmax over cols (valid < 196), scale applied inside exp ----
    const int rb = wr + lg * 4;
    #pragma unroll
    for (int m = 0; m < 4; m++)
        #pragma unroll
        for (int i = 0; i < 4; i++) {
            float mx = -1e30f;
            #pragma unroll
            for (int n = 0; n < 4; n++) {
                int c0 = wc + 16 * n + lr;
                if (c0 < 196) mx = fmaxf(mx, acc0[m][n][i]);
                if (c0 + 128 < 196) mx = fmaxf(mx, acc1[m][n][i]);
            }
            #pragma unroll
            for (int o = 1; o < 16; o <<= 1) mx = fmaxf(mx, __shfl_xor(mx, o));
            if (lr == 0) part[0][rb + 16 * m + i][wave & 1] = mx;
        }
    __syncthreads();
    #pragma unroll
    for (int m = 0; m < 4; m++)
        #pragma unroll
        for (int i = 0; i < 4; i++) {
            int row = rb + 16 * m + i;
            float rmx = fmaxf(part[0][row][0], part[0][row][1]);
            float s = 0.f;
            #pragma unroll
            for (int n = 0; n < 4; n++) {
                int c0 = wc + 16 * n + lr;
                float e0 = (c0 < 196) ? __expf((acc0[m][n][i] - rmx) * SM_SCALE) : 0.f;
                float e1 = (c0 + 128 < 196) ? __expf((acc1[m][n][i] - rmx) * SM_SCALE) : 0.f;
                acc0[m][n][i] = e0; acc1[m][n][i] = e1;
                s += e0 + e1;
            }
            #pragma unroll
            for (int o = 1; o < 16; o <<= 1) s += __shfl_xor(s, o);
            if (lr == 0) part[1][row][wave & 1] = s;
        }
    __syncthreads();
    #pragma unroll
    for (int m = 0; m < 4; m++)
        #pragma unroll
        for (int i = 0; i < 4; i++) {
            int row = rb + 16 * m + i;
            float inv = 1.f / (part[1][row][0] + part[1][row][1]);
            #pragma unroll
            for (int n = 0; n < 4; n++) {
                int c0 = wc + 16 * n + lr;
                Pl[row * 232 + c0] = f2bf(acc0[m][n][i] * inv);
                if (c0 + 128 < 224)
                    Pl[row * 232 + c0 + 128] = f2bf(acc1[m][n][i] * inv);
            }
        }
    // part[] now free: zero it for ykv row-stats accumulation
    __syncthreads();
    { float* pf = &part[0][0][0]; pf[tid] = 0.f; pf[tid + 256] = 0.f; }
    // ---- PV: O[row,d] = sum_s P[row,s]*hnT[d][s], 6 col-tiles, K=224 ----
    // reg-staged B into lds_b (linear dest, pre-swizzled global source).
    const int srow = tid >> 2;
    const int gsl = (tid & 3) ^ ((srow >> 1) & 3);
    const int ewr2 = wr + lg * 4, ewc2 = wc + lr;
    for (int cd = 0; cd < 6; ++cd) {
        const u16* Bt = hnT + ((long)bL * 768 + cd * 128) * 224;
        const u16* gb = Bt + (long)srow * 224 + gsl * 8;
        f32x4 pacc[4][4];
        #pragma unroll
        for (int m = 0; m < 4; m++)
            #pragma unroll
            for (int n = 0; n < 4; n++) pacc[m][n] = (f32x4){0.f, 0.f, 0.f, 0.f};
        bf16x8 r0 = *(const bf16x8*)(gb);
        bf16x8 r1 = *(const bf16x8*)(gb + (long)64 * 224);
        __syncthreads();                 // prior pass's lds_b reads done
        *(bf16x8*)(lds_b + tid * 8) = r0;
        *(bf16x8*)(lds_b + 2048 + tid * 8) = r1;
        __syncthreads();
        for (int k0 = 0; k0 < 7; ++k0) {
            if (k0 < 6) {
                r0 = *(const bf16x8*)(gb + (k0 + 1) * 32);
                r1 = *(const bf16x8*)(gb + (long)64 * 224 + (k0 + 1) * 32);
            }
            bf16x8 af[4], bfr[4];
            #pragma unroll
            for (int m = 0; m < 4; m++)
                af[m] = *(const bf16x8*)&Pl[(wr + 16 * m + lr) * 232 + k0 * 32 + lk];
            #pragma unroll
            for (int n = 0; n < 4; n++)
                bfr[n] = *(const bf16x8*)&lds_b[(wc + 16 * n + lr) * 32 + ps];
            #pragma unroll
            for (int m = 0; m < 4; m++)
                #pragma unroll
                for (int n = 0; n < 4; n++)
                    pacc[m][n] = __builtin_amdgcn_mfma_f32_16x16x32_bf16(
                        af[m], bfr[n], pacc[m][n], 0, 0, 0);
            __syncthreads();
            if (k0 < 6) {
                *(bf16x8*)(lds_b + tid * 8) = r0;
                *(bf16x8*)(lds_b + 2048 + tid * 8) = r1;
            }
            __syncthreads();
        }
        // row-stats partials for this 128-col slab (per-thread slots, no race)
        #pragma unroll
        for (int m = 0; m < 4; m++)
            #pragma unroll
            for (int i = 0; i < 4; i++) {
                float s = pacc[m][0][i] + pacc[m][1][i] + pacc[m][2][i] + pacc[m][3][i];
                float q2 = pacc[m][0][i] * pacc[m][0][i] + pacc[m][1][i] * pacc[m][1][i] +
                           pacc[m][2][i] * pacc[m][2][i] + pacc[m][3][i] * pacc[m][3][i];
                #pragma unroll
                for (int o = 1; o < 16; o <<= 1) {
                    s += __shfl_xor(s, o);
                    q2 += __shfl_xor(q2, o);
                }
                if (lr == 0) {
                    part[0][rb + 16 * m + i][wave & 1] += s;
                    part[1][rb + 16 * m + i][wave & 1] += q2;
                }
            }
        #pragma unroll
        for (int m = 0; m < 4; m++)
            #pragma unroll
            for (int n = 0; n < 4; n++)
                #pragma unroll
                for (int i = 0; i < 4; i++) {
                    int trow = row0 + ewr2 + 16 * m + i;
                    if (trow < 196)
                        ykv[((long)bh * 196 + trow) * 768 + cd * 128 + ewc2 + 16 * n] =
                            f2bf(pacc[m][n][i]);
                }
    }
    // finalize row stats
    __syncthreads();
    if (tid < 128) {
        int trow = row0 + tid;
        if (trow < 196) {
            float s = part[0][tid][0] + part[0][tid][1];
            float q2 = part[1][tid][0] + part[1][tid][1];
            float mu = s * (1.f / 768.f);
            float var = q2 * (1.f / 768.f) - mu * mu;
            float2 st;
            st.x = mu;
            st.y = rsqrtf(var + LN_EPS);
            *(float2*)&stats[((long)bh * 196 + trow) * 2] = st;
        }
    }
}

// y_sparse = relu(LN(ykv) @ encv) via fold: rs*(acc - mu*colsum);
// z = x_sparse*y_sparse, head-major flatten. grid (25,4,12), swizzled.
__global__ __launch_bounds__(256) void k_gemm_ys(const u16* __restrict__ ykv,
                                                 const u16* __restrict__ encvt,
                                                 const u16* __restrict__ xs,
                                                 const float* __restrict__ stats,
                                                 const float* __restrict__ colsum,
                                                 u16* __restrict__ z) {
    GEMM64_PROLOGUE
    // XCD swizzle: 1200 wgs, q=150
    int p = blockIdx.x + 25 * (blockIdx.y + 4 * blockIdx.z);
    int w = (p & 7) * 150 + (p >> 3);
    int rt = w % 25, rem = w / 25;
    int ct = rem & 3, h = rem >> 2;
    int row0 = rt * 128, col0 = ct * 128;
    gemm_core64(ykv + ((long)h * MC + row0) * 768, 768,
                encvt + ((long)h * 512 + col0) * 768, 768, 12, acc, lds_a, lds_b);
    EPI_VARS
    const int tid = threadIdx.x;
    u16* TU = lds_ab;                    // [128][128]
    // phase A: vector-load xs tile
    __syncthreads();
    #pragma unroll
    for (int q = 0; q < 8; ++q) {
        int chunk = tid + q * 256;
        int r = chunk >> 4, c = chunk & 15;
        *(bf16x8*)&TU[r * 128 + c * 8] =
            *(const bf16x8*)&xs[((long)h * MC + row0 + r) * 512 + col0 + c * 8];
    }
    __syncthreads();
    // phase B: in-place fold+relu+mul (thread-owned slots)
    #pragma unroll
    for (int m = 0; m < 4; m++)
        #pragma unroll
        for (int i = 0; i < 4; i++) {
            int rloc = ewr + 16 * m + i;
            int row = row0 + rloc;
            float mu = 0.f, rs = 0.f;
            if (row < MC) {
                float2 st = *(const float2*)&stats[((long)h * MC + row) * 2];
                mu = st.x; rs = st.y;
            }
            #pragma unroll
            for (int n = 0; n < 4; n++) {
                int cloc = ewc + 16 * n;
                float cs = colsum[h * 512 + col0 + cloc];
                float v = (acc[m][n][i] - mu * cs) * rs;
                v = fmaxf(v, 0.f) * bf2f(TU[rloc * 128 + cloc]);
                TU[rloc * 128 + cloc] = f2bf(v);
            }
        }
    __syncthreads();
    // phase C: vector-store z tile
    #pragma unroll
    for (int q = 0; q < 8; ++q) {
        int chunk = tid + q * 256;
        int r = chunk >> 4, c = chunk & 15;
        int row = row0 + r;
        if (row < MC)
            *(bf16x8*)&z[(long)row * 6144 + h * 512 + col0 + c * 8] =
                *(bf16x8*)&TU[r * 128 + c * 8];
    }
}

// yMLP_raw partial s = z[:, s*1536:(s+1)*1536] @ dec[s...]  (split-K4)
__global__ __launch_bounds__(256) void k_gemm_mlp(const u16* __restrict__ z,
                                                  const u16* __restrict__ dect,
                                                  float* __restrict__ rawK) {
    GEMM64_PROLOGUE
    // XCD swizzle: grid (25,6,4) -> 600 wgs, q=75
    int p = blockIdx.x + 25 * (blockIdx.y + 6 * blockIdx.z);
    int w = (p & 7) * 75 + (p >> 3);
    int row0 = (w % 25) * 128, col0 = ((w / 25) % 6) * 128, s = w / 150;
    gemm_core64(z + (long)row0 * 6144 + s * 1536, 6144,
                dect + (long)col0 * 6144 + s * 1536, 6144, 24, acc, lds_a, lds_b);
    EPI_VARS
    const int tid = threadIdx.x;
    float* TF = (float*)lds_ab;          // [64][128] f32, two half-passes
    float* raw = rawK + (long)s * MC * 768;
    #pragma unroll
    for (int hf = 0; hf < 2; ++hf) {
        __syncthreads();
        if ((ewr >> 6) == hf) {
            #pragma unroll
            for (int m = 0; m < 4; m++)
                #pragma unroll
                for (int n = 0; n < 4; n++)
                    #pragma unroll
                    for (int i = 0; i < 4; i++)
                        TF[(ewr - hf * 64 + 16 * m + i) * 128 + ewc + 16 * n] =
                            acc[m][n][i];
        }
        __syncthreads();
        #pragma unroll
        for (int q = 0; q < 8; ++q) {
            int chunk = tid + q * 256;
            int r = chunk >> 5, c = chunk & 31;
            int row = row0 + hf * 64 + r;
            if (row < MC)
                *(f32x4*)&raw[(long)row * 768 + col0 + c * 4] =
                    *(f32x4*)&TF[r * 128 + c * 4];
        }
    }
}

// ---------------------------------------------------------------------------
// per-row LN kernels
// ---------------------------------------------------------------------------
// hn = LN(h) -> hn bf16 (used ONCE after tokens; later layers skip: LN(LN)~id)
__global__ __launch_bounds__(256) void k_ln1(const float* __restrict__ h,
                                             u16* __restrict__ hnb) {
    __shared__ float sm[4];
    int r = blockIdx.x, tid = threadIdx.x;
    const float* p = h + (long)r * 768;
    float x0 = p[tid], x1 = p[tid + 256], x2 = p[tid + 512];
    float mean = block_reduce_sum(x0 + x1 + x2, sm) * (1.f / 768.f);
    float d0 = x0 - mean, d1 = x1 - mean, d2 = x2 - mean;
    float var = block_reduce_sum(d0 * d0 + d1 * d1 + d2 * d2, sm) * (1.f / 768.f);
    float rs = rsqrtf(var + LN_EPS);
    long ro = (long)r * 768;
    hnb[ro + tid] = f2bf(d0 * rs);
    hnb[ro + tid + 256] = f2bf(d1 * rs);
    hnb[ro + tid + 512] = f2bf(d2 * rs);
}

// hnT[b][d][tpad224] = hnb[b*196+t][d], t-pad zero-filled. 32x32 LDS tiles.
__global__ __launch_bounds__(256) void k_hnT(const u16* __restrict__ hnb,
                                             u16* __restrict__ hnT) {
    __shared__ u16 tile[32][33];
    int t0 = blockIdx.x * 32, d0 = blockIdx.y * 32, b = blockIdx.z;
    int i = threadIdx.x >> 5, j = threadIdx.x & 31;
    #pragma unroll
    for (int p = 0; p < 4; p++) {
        int t = t0 + i + p * 8;
        tile[i + p * 8][j] = (t < 196) ? hnb[((long)b * 196 + t) * 768 + d0 + j] : (u16)0;
    }
    __syncthreads();
    #pragma unroll
    for (int p = 0; p < 4; p++) {
        int dd = i + p * 8;
        hnT[((long)b * 768 + d0 + dd) * 224 + t0 + j] = tile[j][dd];
    }
}

// hnb = LN(hnb + LN(sum of 4 split-K partials))  [in-place: reads first]
__global__ __launch_bounds__(256) void k_final_h(const float* __restrict__ rawK,
                                                 u16* __restrict__ hnb) {
    __shared__ float sm[4];
    const long PS = (long)MC * 768;
    int r = blockIdx.x, tid = threadIdx.x;
    const float* rp = rawK + (long)r * 768;
    u16* hp = hnb + (long)r * 768;
    float y0 = rp[tid] + rp[tid + PS] + rp[tid + 2 * PS] + rp[tid + 3 * PS];
    float y1 = rp[tid + 256] + rp[tid + 256 + PS] + rp[tid + 256 + 2 * PS] + rp[tid + 256 + 3 * PS];
    float y2 = rp[tid + 512] + rp[tid + 512 + PS] + rp[tid + 512 + 2 * PS] + rp[tid + 512 + 3 * PS];
    float h0 = bf2f(hp[tid]), h1 = bf2f(hp[tid + 256]), h2 = bf2f(hp[tid + 512]);
    float mean = block_reduce_sum(y0 + y1 + y2, sm) * (1.f / 768.f);
    float d0 = y0 - mean, d1 = y1 - mean, d2 = y2 - mean;
    float var = block_reduce_sum(d0 * d0 + d1 * d1 + d2 * d2, sm) * (1.f / 768.f);
    float rs = rsqrtf(var + LN_EPS);
    float s0 = h0 + d0 * rs;
    float s1 = h1 + d1 * rs;
    float s2 = h2 + d2 * rs;
    mean = block_reduce_sum(s0 + s1 + s2, sm) * (1.f / 768.f);
    d0 = s0 - mean; d1 = s1 - mean; d2 = s2 - mean;
    var = block_reduce_sum(d0 * d0 + d1 * d1 + d2 * d2, sm) * (1.f / 768.f);
    rs = rsqrtf(var + LN_EPS);
    hp[tid] = f2bf(d0 * rs);
    hp[tid + 256] = f2bf(d1 * rs);
    hp[tid + 512] = f2bf(d2 * rs);
}

// pool stage 1: partial sums over 14-row groups -> part[b][g][768] (bf16 in)
__global__ __launch_bounds__(256) void k_pool1(const u16* __restrict__ hnb,
                                               float* __restrict__ part) {
    int g = blockIdx.x, b = blockIdx.y, tid = threadIdx.x;
    const u16* base = hnb + ((long)b * 196 + g * 14) * 768;
    float a0 = 0.f, a1 = 0.f, a2 = 0.f;
    for (int t = 0; t < 14; t++) {
        const u16* p = base + (long)t * 768;
        a0 += bf2f(p[tid]); a1 += bf2f(p[tid + 256]); a2 += bf2f(p[tid + 512]);
    }
    float* pp = part + ((long)b * 14 + g) * 768;
    pp[tid] = a0; pp[tid + 256] = a1; pp[tid + 512] = a2;
}

// pool stage 2: pooled = LN(sum(part)/196)
__global__ __launch_bounds__(256) void k_pool2(const float* __restrict__ part,
                                               float* __restrict__ pooled) {
    __shared__ float sm[4];
    int b = blockIdx.x, tid = threadIdx.x;
    const float* pp = part + (long)b * 14 * 768;
    float a0 = 0.f, a1 = 0.f, a2 = 0.f;
    for (int g = 0; g < 14; g++) {
        a0 += pp[g * 768 + tid]; a1 += pp[g * 768 + tid + 256]; a2 += pp[g * 768 + tid + 512];
    }
    a0 *= (1.f / 196.f); a1 *= (1.f / 196.f); a2 *= (1.f / 196.f);
    float mean = block_reduce_sum(a0 + a1 + a2, sm) * (1.f / 768.f);
    float d0 = a0 - mean, d1 = a1 - mean, d2 = a2 - mean;
    float var = block_reduce_sum(d0 * d0 + d1 * d1 + d2 * d2, sm) * (1.f / 768.f);
    float rs = rsqrtf(var + LN_EPS);
    pooled[(long)b * 768 + tid] = d0 * rs;
    pooled[(long)b * 768 + tid + 256] = d1 * rs;
    pooled[(long)b * 768 + tid + 512] = d2 * rs;
}

// out = pooled @ head_w^T + head_b.  grid (250, 64): wave w -> col 4*bx+w.
__global__ __launch_bounds__(256) void k_head(const float* __restrict__ pooled,
                                              const float* __restrict__ hw,
                                              const float* __restrict__ hb,
                                              float* __restrict__ out) {
    __shared__ float pr[768];
    int b = blockIdx.y, tid = threadIdx.x;
    pr[tid] = pooled[(long)b * 768 + tid];
    pr[tid + 256] = pooled[(long)b * 768 + tid + 256];
    pr[tid + 512] = pooled[(long)b * 768 + tid + 512];
    __syncthreads();
    int c = blockIdx.x * 4 + (tid >> 6);
    int lane = tid & 63;
    const float* wrow = hw + (long)c * 768;
    float acc = 0.f;
    #pragma unroll
    for (int k = 0; k < 768; k += 64) acc += pr[k + lane] * wrow[k + lane];
    #pragma unroll
    for (int o = 32; o; o >>= 1) acc += __shfl_xor(acc, o);
    if (lane == 0) out[(long)b * 1000 + c] = acc + hb[c];
}

// ---------------------------------------------------------------------------
extern "C" void kernel_launch(void* const* d_in, const int* in_sizes, int n_in,
                              void* d_out, int out_size, void* d_ws, size_t ws_size,
                              hipStream_t stream) {
    const float* x     = (const float*)d_in[0];
    const float* convw = (const float*)d_in[1];
    const float* convb = (const float*)d_in[2];
    const float* pe    = (const float*)d_in[3];
    const float* enc   = (const float*)d_in[4];
    const float* encv  = (const float*)d_in[5];
    const float* dec   = (const float*)d_in[6];
    const float* freqs = (const float*)d_in[7];
    const float* hw    = (const float*)d_in[8];
    const float* hbias = (const float*)d_in[9];
    float* out = (float*)d_out;

    char* W = (char*)d_ws;
    size_t off = 0;
    auto ALLOC = [&](size_t bytes) {
        size_t o = off;
        off += (bytes + 255) & ~(size_t)255;
        return o;
    };
    // persistent
    float* bh    = (float*)(W + ALLOC(38535168));            // h f32 (setup only)
    u16*   bhnb  = (u16*)  (W + ALLOC(19267584 + 524288));   // hn bf16 (+edge slack)
    u16*   bhnT  = (u16*)  (W + ALLOC(22020096));            // hn^T bf16 (64,768,224)
    u16*   benc  = (u16*)  (W + ALLOC(9437184));             // enc^T  (12,512,768)
    u16*   bencv = (u16*)  (W + ALLOC(9437184));             // encv^T
    u16*   bdec  = (u16*)  (W + ALLOC(9437184));             // dec^T  (768,6144)
    float* btc   = (float*)(W + ALLOC(401408));              // cos (196,512)
    float* bts   = (float*)(W + ALLOC(401408));              // sin
    float* bpool = (float*)(W + ALLOC(196608));              // pooled (64,768)
    float* bpart = (float*)(W + ALLOC(2752512));             // pool partials (64,14,768)
    float* bstats= (float*)(W + ALLOC(301056));              // ykv row stats (192*196 x f32x2)
    float* bcs   = (float*)(W + ALLOC(24576));               // encv colsums (12,512)
    // chunk regions (+slack for masked edge-tile overreads)
    char*  R1    = (char*) (W + ALLOC(38535168 + 2097152));  // qr / z
    char*  R2    = (char*) (W + ALLOC(57802752 + 524288));   // ykv / rawK (+setup patches)
    char*  R3    = (char*) (W + ALLOC(38535168 + 524288));   // xs (+setup conv_w)
    (void)ws_size; (void)in_sizes; (void)n_in; (void)out_size;

    u16*   bap  = (u16*)R2;    // setup: packed patches (18.4M)
    u16*   bcw  = (u16*)R3;    // setup: conv_w bf16 (1.2M)
    u16*   qr   = (u16*)R1;    // per-chunk head-major (192hb,196,512)
    u16*   z    = (u16*)R1;    // (3136,6144)
    u16*   ykv  = (u16*)R2;    // head-major (192hb,196,768)
    float* rawK = (float*)R2;  // yMLP split-K partials 4x(3136,768) f32
    u16*   xs   = (u16*)R3;    // head-major (192hb,196,512)

    // ---- setup ----
    k_pack_patches<<<37632, 256, 0, stream>>>(x, bap);
    k_cast<<<2304, 256, 0, stream>>>(convw, bcw, 768 * 768);
    k_gemm_tokens<<<dim3(98, 6), 256, 0, stream>>>(bap, bcw, convb, pe, bh);
    k_transpose_cast<<<dim3(16, 24, 12), 256, 0, stream>>>(enc, benc, 768, 512);
    k_transpose_cast<<<dim3(16, 24, 12), 256, 0, stream>>>(encv, bencv, 768, 512);
    k_transpose_cast<<<dim3(24, 192, 1), 256, 0, stream>>>(dec, bdec, 6144, 768);
    k_rope_tab<<<392, 256, 0, stream>>>(freqs, btc, bts);
    k_colsum<<<dim3(2, 12), 256, 0, stream>>>(encv, bcs);
    k_ln1<<<12544, 256, 0, stream>>>(bh, bhnb);   // once; thereafter LN(LN)~id

    // ---- 6 shared-weight layers, 4 chunks of 16 images each ----
    for (int L = 0; L < 6; ++L) {
        k_hnT<<<dim3(7, 24, 64), 256, 0, stream>>>(bhnb, bhnT);
        for (int c = 0; c < 4; ++c) {
            long r0 = (long)c * MC;                    // chunk row offset
            k_gemm_xs<<<dim3(25, 48), 256, 0, stream>>>(
                bhnb + r0 * 768, benc, btc, bts, xs, qr);
            k_attn<<<dim3(2, 192), 256, 0, stream>>>(
                qr, bhnT + (long)c * 16 * 768 * 224, ykv, bstats);
            k_gemm_ys<<<dim3(25, 4, 12), 256, 0, stream>>>(ykv, bencv, xs, bstats, bcs, z);
            k_gemm_mlp<<<dim3(25, 6, 4), 256, 0, stream>>>(z, bdec, rawK);
            k_final_h<<<MC, 256, 0, stream>>>(rawK, bhnb + r0 * 768);
        }
    }

    // ---- head ----
    k_pool1<<<dim3(14, 64), 256, 0, stream>>>(bhnb, bpart);
    k_pool2<<<64, 256, 0, stream>>>(bpart, bpool);
    k_head<<<dim3(250, 64), 256, 0, stream>>>(bpool, hw, hbias, out);
}

// Round 8
// 6049.381 us; speedup vs baseline: 1.3698x; 1.2581x over previous
//
#include <hip/hip_runtime.h>
#include <hip/hip_bf16.h>

// ============================================================================
// VisionBDHv2 forward, MI355X (gfx950). Round 15.
// R11: 6880us (BEST, proven). R12/R13/R14: attn scheduling attempts all flat
// or worse -- attn is latency/locality-bound (conflicts 3.6M vs 1.0M at the
// SAME 98us). R14 also reproved m151: gload_lds > reg-staging at 128x128.
// R15 = R11 exact +:
//   1) attn XCD/bL-locality remap: 1D grid 384, xcd = p&7; each XCD gets
//      2 bL x 12 h x 2 rt -> all consumers of an hnT[bL] slab (344KB, 24
//      blocks) and each qr slab (200KB, rt-pairs) share one XCD L2.
//   2) k_gemm_xs rope pass vectorized: read xs tile from TU, f32x4 table
//      loads, in-register pair-rotate (no shuffle), direct qr store.
//      Removes 128 scalar table loads/thread + one barrier + one acc pass.
// ============================================================================

typedef short bf16x8 __attribute__((ext_vector_type(8)));
typedef float f32x4 __attribute__((ext_vector_type(4)));
typedef unsigned short u16;

#define LN_EPS 1e-5f
#define SM_SCALE 0.044194173824159216f  /* 1/sqrt(512) */
#define TWO_PI 6.283185307179586f
#define MC 3136                          /* rows per chunk = 16*196 */

typedef __attribute__((address_space(3))) unsigned char* as3p;
typedef const __attribute__((address_space(1))) unsigned char* as1p;

__device__ __forceinline__ void gload16(const u16* g, u16* l) {
    __builtin_amdgcn_global_load_lds((as1p)(const void*)g, (as3p)(void*)l, 16, 0, 0);
}

__device__ __forceinline__ u16 f2bf(float f) {
    __hip_bfloat16 h = __float2bfloat16(f);
    return *reinterpret_cast<u16*>(&h);
}
__device__ __forceinline__ float bf2f(u16 u) {
    return __uint_as_float(((unsigned)u) << 16);
}

// ---------------------------------------------------------------------------
// block reductions (256 threads, 4 waves)
// ---------------------------------------------------------------------------
__device__ __forceinline__ float block_reduce_sum(float v, float* sm) {
    #pragma unroll
    for (int o = 32; o; o >>= 1) v += __shfl_xor(v, o);
    if ((threadIdx.x & 63) == 0) sm[threadIdx.x >> 6] = v;
    __syncthreads();
    float r = sm[0] + sm[1] + sm[2] + sm[3];
    __syncthreads();
    return r;
}

// ---------------------------------------------------------------------------
// GEMM core (R7/R11 gemm_core64, verbatim): BK=64, swizzled, 128x128 tile,
// 4 waves (2x2). LDS [128][64] u16 per operand; physical slot s holds
// logical col-slot s^(row&7). Staged via global_load_lds with pre-swizzled
// global source (linear LDS dest). ds_read applies same XOR. C/D: elem i ->
// row (lane>>4)*4+i, col lane&15.
// ---------------------------------------------------------------------------
__device__ __forceinline__ void gemm_core64(const u16* __restrict__ A, int lda,
                                            const u16* __restrict__ Bt, int ldb,
                                            int ksteps, f32x4 acc[4][4],
                                            u16* lds_a, u16* lds_b) {
    const int tid = threadIdx.x;
    const int lane = tid & 63;
    const int wave = tid >> 6;
    const int wr = (wave >> 1) * 64;
    const int wc = (wave & 1) * 64;
    const int lr = lane & 15;
    const int lg = lane >> 4;            // logical k-slot base (0..3)
    const int rx = lr & 7;               // row&7 for this lane's fragment rows
    const int srow = tid >> 3;           // staging row within 32-row group
    const int gslot = (tid & 7) ^ (srow & 7);  // pre-swizzled global col slot
    const u16* ga = A + (long)srow * lda + gslot * 8;
    const u16* gb = Bt + (long)srow * ldb + gslot * 8;
    u16* la = lds_a + tid * 8;           // linear dest: row srow, slot tid&7
    u16* lb = lds_b + tid * 8;
    for (int k0 = 0; k0 < ksteps; ++k0) {
        __syncthreads();                 // prior iteration's reads done
        #pragma unroll
        for (int j = 0; j < 4; ++j) {    // 32-row groups (row&7 invariant)
            gload16(ga + (long)(j * 32) * lda, la + j * 2048);
            gload16(gb + (long)(j * 32) * ldb, lb + j * 2048);
        }
        ga += 64; gb += 64;
        __syncthreads();                 // drains vmcnt(0) before barrier
        bf16x8 af[2][4], bfr[2][4];
        #pragma unroll
        for (int kk = 0; kk < 2; ++kk) {
            const int ps = ((lg + kk * 4) ^ rx) * 8;   // physical elem offset
            #pragma unroll
            for (int m = 0; m < 4; m++)
                af[kk][m] = *(const bf16x8*)&lds_a[(wr + 16 * m + lr) * 64 + ps];
            #pragma unroll
            for (int n = 0; n < 4; n++)
                bfr[kk][n] = *(const bf16x8*)&lds_b[(wc + 16 * n + lr) * 64 + ps];
        }
        #pragma unroll
        for (int kk = 0; kk < 2; ++kk)
            #pragma unroll
            for (int m = 0; m < 4; m++)
                #pragma unroll
                for (int n = 0; n < 4; n++)
                    acc[m][n] = __builtin_amdgcn_mfma_f32_16x16x32_bf16(
                        af[kk][m], bfr[kk][n], acc[m][n], 0, 0, 0);
    }
}

// merged 32KB LDS: gemm uses [lds_a | lds_b]; epilogue reuses as one tile
// (TU u16[128][128] or TF f32[64][128]).
#define GEMM64_PROLOGUE                                 \
    __shared__ alignas(16) u16 lds_ab[2 * 128 * 64];    \
    u16* lds_a = lds_ab;                                \
    u16* lds_b = lds_ab + 128 * 64;                     \
    f32x4 acc[4][4];                                    \
    _Pragma("unroll")                                   \
    for (int m = 0; m < 4; m++)                         \
        _Pragma("unroll")                               \
        for (int n = 0; n < 4; n++)                     \
            acc[m][n] = (f32x4){0.f, 0.f, 0.f, 0.f};

#define EPI_VARS                                        \
    const int lane = threadIdx.x & 63;                  \
    const int wave = threadIdx.x >> 6;                  \
    const int ewr = (wave >> 1) * 64 + (lane >> 4) * 4; \
    const int ewc = (wave & 1) * 64 + (lane & 15);

// ---------------------------------------------------------------------------
// GEMM core v2 (BK=32, linear, 256 threads) — used by k_attn only (R11).
// ---------------------------------------------------------------------------
__device__ __forceinline__ void gemm_core(const u16* __restrict__ A, int lda,
                                          const u16* __restrict__ Bt, int ldb,
                                          int ksteps, f32x4 acc[4][4],
                                          u16* lds_a, u16* lds_b) {
    const int tid = threadIdx.x;
    const int lane = tid & 63;
    const int wave = tid >> 6;
    const int wr = (wave >> 1) * 64;
    const int wc = (wave & 1) * 64;
    const int lr = lane & 15;
    const int lk = (lane >> 4) * 8;
    const int srow = tid >> 2;
    const int scol = (tid & 3) * 8;
    const u16* ga = A + (long)srow * lda + scol;
    const u16* gb = Bt + (long)srow * ldb + scol;
    const long ha = (long)64 * lda;
    const long hb = (long)64 * ldb;
    u16* la = lds_a + tid * 8;
    u16* lb = lds_b + tid * 8;
    for (int k0 = 0; k0 < ksteps; ++k0) {
        __syncthreads();
        gload16(ga, la);
        gload16(ga + ha, la + 2048);
        gload16(gb, lb);
        gload16(gb + hb, lb + 2048);
        ga += 32; gb += 32;
        __syncthreads();
        bf16x8 af[4], bfr[4];
        #pragma unroll
        for (int m = 0; m < 4; m++)
            af[m] = *(const bf16x8*)&lds_a[(wr + 16 * m + lr) * 32 + lk];
        #pragma unroll
        for (int n = 0; n < 4; n++)
            bfr[n] = *(const bf16x8*)&lds_b[(wc + 16 * n + lr) * 32 + lk];
        #pragma unroll
        for (int m = 0; m < 4; m++)
            #pragma unroll
            for (int n = 0; n < 4; n++)
                acc[m][n] = __builtin_amdgcn_mfma_f32_16x16x32_bf16(af[m], bfr[n], acc[m][n], 0, 0, 0);
    }
}

// ---------------------------------------------------------------------------
// setup kernels
// ---------------------------------------------------------------------------
__global__ __launch_bounds__(256) void k_pack_patches(const float* __restrict__ x,
                                                      u16* __restrict__ ap) {
    int idx = blockIdx.x * 256 + threadIdx.x;           // < 12544*768
    int r = idx / 768, k = idx - r * 768;
    int b = r / 196, t = r - b * 196;
    int hp = t / 14, wp = t - hp * 14;
    int c = k >> 8, rem = k & 255, p = rem >> 4, q = rem & 15;
    long src = ((long)(b * 3 + c) * 224 + hp * 16 + p) * 224 + wp * 16 + q;
    ap[idx] = f2bf(x[src]);
}

__global__ __launch_bounds__(256) void k_cast(const float* __restrict__ s,
                                              u16* __restrict__ d, int n) {
    int i = blockIdx.x * 256 + threadIdx.x;
    if (i < n) d[i] = f2bf(s[i]);
}

// src (batch, R, C) f32 -> dst (batch, C, R) bf16
__global__ __launch_bounds__(256) void k_transpose_cast(const float* __restrict__ src,
                                                        u16* __restrict__ dst,
                                                        int R, int C) {
    __shared__ float tile[32][33];
    int c0 = blockIdx.x * 32, r0 = blockIdx.y * 32;
    long base = (long)blockIdx.z * R * C;
    int i = threadIdx.x >> 5, j = threadIdx.x & 31;
    #pragma unroll
    for (int p = 0; p < 4; p++) {
        int rr = i + p * 8;
        tile[rr][j] = src[base + (long)(r0 + rr) * C + c0 + j];
    }
    __syncthreads();
    #pragma unroll
    for (int p = 0; p < 4; p++) {
        int rr = i + p * 8;
        dst[base + (long)(c0 + rr) * R + r0 + j] = f2bf(tile[j][rr]);
    }
}

__global__ __launch_bounds__(256) void k_rope_tab(const float* __restrict__ freqs,
                                                  float* __restrict__ tc,
                                                  float* __restrict__ ts) {
    int idx = blockIdx.x * 256 + threadIdx.x;           // < 196*512
    int t = idx >> 9, n = idx & 511;
    float ph = (float)t * freqs[n];
    ph = (ph - floorf(ph)) * TWO_PI;
    tc[idx] = cosf(ph);
    ts[idx] = sinf(ph);
}

// colsum[h][c] = sum_d encv[h][d][c]  (from f32 encv, coalesced in c)
__global__ __launch_bounds__(256) void k_colsum(const float* __restrict__ encv,
                                                float* __restrict__ cs) {
    int h = blockIdx.y, c = blockIdx.x * 256 + threadIdx.x;   // grid (2,12)
    const float* base = encv + (long)h * 768 * 512 + c;
    float a = 0.f;
    for (int d = 0; d < 768; d++) a += base[(long)d * 512];
    cs[h * 512 + c] = a;
}

// ---------------------------------------------------------------------------
// GEMM kernels (R11 core + LDS-bounce epilogues)
// ---------------------------------------------------------------------------
// tokens = patches @ convw^T + bias + pos_embed -> h   (M=12544,K=768,N=768)
__global__ __launch_bounds__(256) void k_gemm_tokens(const u16* __restrict__ ap,
                                                     const u16* __restrict__ bw,
                                                     const float* __restrict__ cb,
                                                     const float* __restrict__ pe,
                                                     float* __restrict__ hout) {
    GEMM64_PROLOGUE
    int row0 = blockIdx.x * 128, col0 = blockIdx.y * 128;
    gemm_core64(ap + (long)row0 * 768, 768, bw + (long)col0 * 768, 768, 12, acc, lds_a, lds_b);
    EPI_VARS
    const int tid = threadIdx.x;
    float* TF = (float*)lds_ab;          // [64][128] f32, two half-passes
    #pragma unroll
    for (int hf = 0; hf < 2; ++hf) {
        __syncthreads();
        if ((ewr >> 6) == hf) {
            #pragma unroll
            for (int m = 0; m < 4; m++)
                #pragma unroll
                for (int n = 0; n < 4; n++)
                    #pragma unroll
                    for (int i = 0; i < 4; i++) {
                        int row = row0 + ewr + 16 * m + i;
                        int col = col0 + ewc + 16 * n;
                        int t = row % 196;
                        TF[(ewr - hf * 64 + 16 * m + i) * 128 + ewc + 16 * n] =
                            acc[m][n][i] + cb[col] + pe[t * 768 + col];
                    }
        }
        __syncthreads();
        #pragma unroll
        for (int q = 0; q < 8; ++q) {
            int chunk = tid + q * 256;   // 64 rows x 32 chunks (16B=4 f32)
            int r = chunk >> 5, c = chunk & 31;
            *(f32x4*)&hout[(long)(row0 + hf * 64 + r) * 768 + col0 + c * 4] =
                *(f32x4*)&TF[r * 128 + c * 4];
        }
    }
}

// chunk: x_sparse = relu(hn@enc); qr = rope(x_sparse)  (M=3136 masked, N=6144)
// xs/qr written HEAD-MAJOR: [(head*16+bL)*196 + t][512]
// R15: rope pass vectorized (TU readback + f32x4 tables + in-reg pair rotate)
__global__ __launch_bounds__(256) void k_gemm_xs(const u16* __restrict__ hnb,
                                                 const u16* __restrict__ enct,
                                                 const float* __restrict__ tc,
                                                 const float* __restrict__ tsn,
                                                 u16* __restrict__ xs,
                                                 u16* __restrict__ qr) {
    GEMM64_PROLOGUE
    // XCD swizzle: grid (25,48) -> 1200 wgs, q=150
    int p = blockIdx.x + 25 * blockIdx.y;
    int w = (p & 7) * 150 + (p >> 3);
    int row0 = (w % 25) * 128, col0 = (w / 25) * 128;
    int head = col0 >> 9, nn0 = col0 & 511;
    gemm_core64(hnb + (long)row0 * 768, 768,
                enct + ((long)head * 512 + nn0) * 768, 768, 12, acc, lds_a, lds_b);
    EPI_VARS
    const int tid = threadIdx.x;
    u16* TU = lds_ab;                    // [128][128] u16
    // ---- pass 1: xs = relu(acc) -> TU -> vector store ----
    __syncthreads();
    #pragma unroll
    for (int m = 0; m < 4; m++)
        #pragma unroll
        for (int n = 0; n < 4; n++)
            #pragma unroll
            for (int i = 0; i < 4; i++)
                TU[(ewr + 16 * m + i) * 128 + ewc + 16 * n] =
                    f2bf(fmaxf(acc[m][n][i], 0.f));
    __syncthreads();
    #pragma unroll
    for (int q = 0; q < 8; ++q) {
        int chunk = tid + q * 256;       // 128 rows x 16 chunks (16B=8 u16)
        int r = chunk >> 4, c = chunk & 15;
        int row = row0 + r;
        if (row < MC)
            *(bf16x8*)&xs[((long)head * MC + row) * 512 + nn0 + c * 8] =
                *(bf16x8*)&TU[r * 128 + c * 8];
    }
    // ---- pass 2: qr = rope(TU) -- reads TU only, vectorized tables ----
    #pragma unroll
    for (int q = 0; q < 8; ++q) {
        int chunk = tid + q * 256;
        int r = chunk >> 4, c = chunk & 15;
        int row = row0 + r;
        if (row < MC) {
            int t = row % 196;
            int nn = nn0 + c * 8;
            bf16x8 v8 = *(bf16x8*)&TU[r * 128 + c * 8];
            f32x4 cs0 = *(const f32x4*)&tc[t * 512 + nn];
            f32x4 cs1 = *(const f32x4*)&tc[t * 512 + nn + 4];
            f32x4 sn0 = *(const f32x4*)&tsn[t * 512 + nn];
            f32x4 sn1 = *(const f32x4*)&tsn[t * 512 + nn + 4];
            float v[8], qv[8];
            #pragma unroll
            for (int j = 0; j < 8; j++) v[j] = bf2f((u16)v8[j]);
            #pragma unroll
            for (int j = 0; j < 2; j++) {
                qv[2 * j]     = v[2 * j] * cs0[2 * j]     - v[2 * j + 1] * sn0[2 * j];
                qv[2 * j + 1] = v[2 * j + 1] * cs0[2 * j + 1] + v[2 * j] * sn0[2 * j + 1];
                qv[4 + 2 * j]     = v[4 + 2 * j] * cs1[2 * j]     - v[4 + 2 * j + 1] * sn1[2 * j];
                qv[4 + 2 * j + 1] = v[4 + 2 * j + 1] * cs1[2 * j + 1] + v[4 + 2 * j] * sn1[2 * j + 1];
            }
            bf16x8 o8;
            #pragma unroll
            for (int j = 0; j < 8; j++) o8[j] = (short)f2bf(qv[j]);
            *(bf16x8*)&qr[((long)head * MC + row) * 512 + nn] = o8;
        }
    }
}

// ---------------------------------------------------------------------------
// Fused attention + ykv row stats (mu, rs) for the ys LN-fold.
// R11 structure. R15: 1D grid 384 with XCD/bL-locality remap — each XCD k
// gets bL in {2k, 2k+1} x all 12 heads x both row tiles, so the 24 consumers
// of each hnT[bL] slab (344KB) and each rt-pair's qr slab share one L2.
// ---------------------------------------------------------------------------
__global__ __launch_bounds__(256) void k_attn(const u16* __restrict__ qr,
                                              const u16* __restrict__ hnT,
                                              u16* __restrict__ ykv,
                                              float* __restrict__ stats) {
    __shared__ alignas(16) u16 lds_a[128 * 32];
    __shared__ alignas(16) u16 lds_b[128 * 32];
    __shared__ alignas(16) u16 Pl[128 * 232];
    __shared__ float part[2][128][2];    // [max|sum][row][wave-col-half]
    const int tid = threadIdx.x, lane = tid & 63, wave = tid >> 6;
    const int wr = (wave >> 1) * 64, wc = (wave & 1) * 64;
    const int lr = lane & 15, lk = (lane >> 4) * 8;
    // XCD/bL-locality remap (bijective over 384)
    const int p = blockIdx.x;            // 0..383
    const int xcd = p & 7, slot = p >> 3;          // 8 x 48
    const int bL = 2 * xcd + (slot >= 24);
    const int sub = (slot >= 24) ? slot - 24 : slot;   // 0..23
    const int h = sub >> 1, rt = sub & 1;
    const int bh = h * 16 + bL;
    const int row0 = rt * 128;
    const u16* qbase = qr + (long)bh * 196 * 512;

    f32x4 acc0[4][4], acc1[4][4];
    #pragma unroll
    for (int m = 0; m < 4; m++)
        #pragma unroll
        for (int n = 0; n < 4; n++) {
            acc0[m][n] = (f32x4){0.f, 0.f, 0.f, 0.f};
            acc1[m][n] = (f32x4){0.f, 0.f, 0.f, 0.f};
        }
    // scores: S[row, col] = Q[row0+row] . Q[col], two 128-col tiles (K=512)
    gemm_core(qbase + (long)row0 * 512, 512, qbase, 512, 16, acc0, lds_a, lds_b);
    gemm_core(qbase + (long)row0 * 512, 512, qbase + 128 * 512, 512, 16, acc1, lds_a, lds_b);

    // ---- softmax over cols (valid < 196), scale applied inside exp ----
    const int rb = wr + (lane >> 4) * 4;
    #pragma unroll
    for (int m = 0; m < 4; m++)
        #pragma unroll
        for (int i = 0; i < 4; i++) {
            float mx = -1e30f;
            #pragma unroll
            for (int n = 0; n < 4; n++) {
                int c0 = wc + 16 * n + lr;
                if (c0 < 196) mx = fmaxf(mx, acc0[m][n][i]);
                if (c0 + 128 < 196) mx = fmaxf(mx, acc1[m][n][i]);
            }
            #pragma unroll
            for (int o = 1; o < 16; o <<= 1) mx = fmaxf(mx, __shfl_xor(mx, o));
            if (lr == 0) part[0][rb + 16 * m + i][wave & 1] = mx;
        }
    __syncthreads();
    #pragma unroll
    for (int m = 0; m < 4; m++)
        #pragma unroll
        for (int i = 0; i < 4; i++) {
            int row = rb + 16 * m + i;
            float rmx = fmaxf(part[0][row][0], part[0][row][1]);
            float s = 0.f;
            #pragma unroll
            for (int n = 0; n < 4; n++) {
                int c0 = wc + 16 * n + lr;
                float e0 = (c0 < 196) ? __expf((acc0[m][n][i] - rmx) * SM_SCALE) : 0.f;
                float e1 = (c0 + 128 < 196) ? __expf((acc1[m][n][i] - rmx) * SM_SCALE) : 0.f;
                acc0[m][n][i] = e0; acc1[m][n][i] = e1;
                s += e0 + e1;
            }
            #pragma unroll
            for (int o = 1; o < 16; o <<= 1) s += __shfl_xor(s, o);
            if (lr == 0) part[1][row][wave & 1] = s;
        }
    __syncthreads();
    #pragma unroll
    for (int m = 0; m < 4; m++)
        #pragma unroll
        for (int i = 0; i < 4; i++) {
            int row = rb + 16 * m + i;
            float inv = 1.f / (part[1][row][0] + part[1][row][1]);
            #pragma unroll
            for (int n = 0; n < 4; n++) {
                int c0 = wc + 16 * n + lr;
                Pl[row * 232 + c0] = f2bf(acc0[m][n][i] * inv);
                if (c0 + 128 < 224)
                    Pl[row * 232 + c0 + 128] = f2bf(acc1[m][n][i] * inv);
            }
        }
    // part[] now free: zero it for ykv row-stats accumulation
    __syncthreads();
    { float* pf = &part[0][0][0]; pf[tid] = 0.f; pf[tid + 256] = 0.f; }
    // ---- PV: O[row, d] = sum_s P[row,s] * hnT[d][s], 6 col-tiles, K=224 ----
    const int srow = tid >> 2, scol = (tid & 3) * 8;
    for (int cd = 0; cd < 6; ++cd) {
        const u16* Bt = hnT + ((long)bL * 768 + cd * 128) * 224;
        f32x4 acc[4][4];
        #pragma unroll
        for (int m = 0; m < 4; m++)
            #pragma unroll
            for (int n = 0; n < 4; n++) acc[m][n] = (f32x4){0.f, 0.f, 0.f, 0.f};
        for (int k0 = 0; k0 < 7; ++k0) {
            __syncthreads();
            gload16(Bt + (long)srow * 224 + k0 * 32 + scol, lds_b + tid * 8);
            gload16(Bt + (long)(srow + 64) * 224 + k0 * 32 + scol, lds_b + 2048 + tid * 8);
            __syncthreads();
            bf16x8 af[4], bfr[4];
            #pragma unroll
            for (int m = 0; m < 4; m++)
                af[m] = *(const bf16x8*)&Pl[(wr + 16 * m + lr) * 232 + k0 * 32 + lk];
            #pragma unroll
            for (int n = 0; n < 4; n++)
                bfr[n] = *(const bf16x8*)&lds_b[(wc + 16 * n + lr) * 32 + lk];
            #pragma unroll
            for (int m = 0; m < 4; m++)
                #pragma unroll
                for (int n = 0; n < 4; n++)
                    acc[m][n] = __builtin_amdgcn_mfma_f32_16x16x32_bf16(af[m], bfr[n], acc[m][n], 0, 0, 0);
        }
        // row-stats partials for this 128-col slab (per-thread slots, no race)
        #pragma unroll
        for (int m = 0; m < 4; m++)
            #pragma unroll
            for (int i = 0; i < 4; i++) {
                float s = acc[m][0][i] + acc[m][1][i] + acc[m][2][i] + acc[m][3][i];
                float q2 = acc[m][0][i] * acc[m][0][i] + acc[m][1][i] * acc[m][1][i] +
                           acc[m][2][i] * acc[m][2][i] + acc[m][3][i] * acc[m][3][i];
                #pragma unroll
                for (int o = 1; o < 16; o <<= 1) {
                    s += __shfl_xor(s, o);
                    q2 += __shfl_xor(q2, o);
                }
                if (lr == 0) {
                    part[0][rb + 16 * m + i][wave & 1] += s;
                    part[1][rb + 16 * m + i][wave & 1] += q2;
                }
            }
        EPI_VARS
        #pragma unroll
        for (int m = 0; m < 4; m++)
            #pragma unroll
            for (int n = 0; n < 4; n++)
                #pragma unroll
                for (int i = 0; i < 4; i++) {
                    int trow = row0 + ewr + 16 * m + i;
                    if (trow < 196)
                        ykv[((long)bh * 196 + trow) * 768 + cd * 128 + ewc + 16 * n] =
                            f2bf(acc[m][n][i]);
                }
    }
    // finalize row stats
    __syncthreads();
    if (tid < 128) {
        int trow = row0 + tid;
        if (trow < 196) {
            float s = part[0][tid][0] + part[0][tid][1];
            float q2 = part[1][tid][0] + part[1][tid][1];
            float mu = s * (1.f / 768.f);
            float var = q2 * (1.f / 768.f) - mu * mu;
            float2 st;
            st.x = mu;
            st.y = rsqrtf(var + LN_EPS);
            *(float2*)&stats[((long)bh * 196 + trow) * 2] = st;
        }
    }
}

// y_sparse = relu(LN(ykv) @ encv) via fold: rs*(acc - mu*colsum);
// z = x_sparse*y_sparse, head-major flatten. grid (25,4,12), swizzled.
__global__ __launch_bounds__(256) void k_gemm_ys(const u16* __restrict__ ykv,
                                                 const u16* __restrict__ encvt,
                                                 const u16* __restrict__ xs,
                                                 const float* __restrict__ stats,
                                                 const float* __restrict__ colsum,
                                                 u16* __restrict__ z) {
    GEMM64_PROLOGUE
    // XCD swizzle: 1200 wgs, q=150
    int p = blockIdx.x + 25 * (blockIdx.y + 4 * blockIdx.z);
    int w = (p & 7) * 150 + (p >> 3);
    int rt = w % 25, rem = w / 25;
    int ct = rem & 3, h = rem >> 2;
    int row0 = rt * 128, col0 = ct * 128;
    gemm_core64(ykv + ((long)h * MC + row0) * 768, 768,
                encvt + ((long)h * 512 + col0) * 768, 768, 12, acc, lds_a, lds_b);
    EPI_VARS
    const int tid = threadIdx.x;
    u16* TU = lds_ab;                    // [128][128]
    // phase A: vector-load xs tile
    __syncthreads();
    #pragma unroll
    for (int q = 0; q < 8; ++q) {
        int chunk = tid + q * 256;
        int r = chunk >> 4, c = chunk & 15;
        *(bf16x8*)&TU[r * 128 + c * 8] =
            *(const bf16x8*)&xs[((long)h * MC + row0 + r) * 512 + col0 + c * 8];
    }
    __syncthreads();
    // phase B: in-place fold+relu+mul (thread-owned slots)
    #pragma unroll
    for (int m = 0; m < 4; m++)
        #pragma unroll
        for (int i = 0; i < 4; i++) {
            int rloc = ewr + 16 * m + i;
            int row = row0 + rloc;
            float mu = 0.f, rs = 0.f;
            if (row < MC) {
                float2 st = *(const float2*)&stats[((long)h * MC + row) * 2];
                mu = st.x; rs = st.y;
            }
            #pragma unroll
            for (int n = 0; n < 4; n++) {
                int cloc = ewc + 16 * n;
                float cs = colsum[h * 512 + col0 + cloc];
                float v = (acc[m][n][i] - mu * cs) * rs;
                v = fmaxf(v, 0.f) * bf2f(TU[rloc * 128 + cloc]);
                TU[rloc * 128 + cloc] = f2bf(v);
            }
        }
    __syncthreads();
    // phase C: vector-store z tile
    #pragma unroll
    for (int q = 0; q < 8; ++q) {
        int chunk = tid + q * 256;
        int r = chunk >> 4, c = chunk & 15;
        int row = row0 + r;
        if (row < MC)
            *(bf16x8*)&z[(long)row * 6144 + h * 512 + col0 + c * 8] =
                *(bf16x8*)&TU[r * 128 + c * 8];
    }
}

// yMLP_raw partial s = z[:, s*1536:(s+1)*1536] @ dec[s...]  (split-K4)
__global__ __launch_bounds__(256) void k_gemm_mlp(const u16* __restrict__ z,
                                                  const u16* __restrict__ dect,
                                                  float* __restrict__ rawK) {
    GEMM64_PROLOGUE
    // XCD swizzle: grid (25,6,4) -> 600 wgs, q=75
    int p = blockIdx.x + 25 * (blockIdx.y + 6 * blockIdx.z);
    int w = (p & 7) * 75 + (p >> 3);
    int row0 = (w % 25) * 128, col0 = ((w / 25) % 6) * 128, s = w / 150;
    gemm_core64(z + (long)row0 * 6144 + s * 1536, 6144,
                dect + (long)col0 * 6144 + s * 1536, 6144, 24, acc, lds_a, lds_b);
    EPI_VARS
    const int tid = threadIdx.x;
    float* TF = (float*)lds_ab;          // [64][128] f32, two half-passes
    float* raw = rawK + (long)s * MC * 768;
    #pragma unroll
    for (int hf = 0; hf < 2; ++hf) {
        __syncthreads();
        if ((ewr >> 6) == hf) {
            #pragma unroll
            for (int m = 0; m < 4; m++)
                #pragma unroll
                for (int n = 0; n < 4; n++)
                    #pragma unroll
                    for (int i = 0; i < 4; i++)
                        TF[(ewr - hf * 64 + 16 * m + i) * 128 + ewc + 16 * n] =
                            acc[m][n][i];
        }
        __syncthreads();
        #pragma unroll
        for (int q = 0; q < 8; ++q) {
            int chunk = tid + q * 256;
            int r = chunk >> 5, c = chunk & 31;
            int row = row0 + hf * 64 + r;
            if (row < MC)
                *(f32x4*)&raw[(long)row * 768 + col0 + c * 4] =
                    *(f32x4*)&TF[r * 128 + c * 4];
        }
    }
}

// ---------------------------------------------------------------------------
// per-row LN kernels
// ---------------------------------------------------------------------------
// hn = LN(h) -> hn bf16 (used ONCE after tokens; later layers skip: LN(LN)~id)
__global__ __launch_bounds__(256) void k_ln1(const float* __restrict__ h,
                                             u16* __restrict__ hnb) {
    __shared__ float sm[4];
    int r = blockIdx.x, tid = threadIdx.x;
    const float* p = h + (long)r * 768;
    float x0 = p[tid], x1 = p[tid + 256], x2 = p[tid + 512];
    float mean = block_reduce_sum(x0 + x1 + x2, sm) * (1.f / 768.f);
    float d0 = x0 - mean, d1 = x1 - mean, d2 = x2 - mean;
    float var = block_reduce_sum(d0 * d0 + d1 * d1 + d2 * d2, sm) * (1.f / 768.f);
    float rs = rsqrtf(var + LN_EPS);
    long ro = (long)r * 768;
    hnb[ro + tid] = f2bf(d0 * rs);
    hnb[ro + tid + 256] = f2bf(d1 * rs);
    hnb[ro + tid + 512] = f2bf(d2 * rs);
}

// hnT[b][d][tpad224] = hnb[b*196+t][d], t-pad zero-filled. 32x32 LDS tiles.
__global__ __launch_bounds__(256) void k_hnT(const u16* __restrict__ hnb,
                                             u16* __restrict__ hnT) {
    __shared__ u16 tile[32][33];
    int t0 = blockIdx.x * 32, d0 = blockIdx.y * 32, b = blockIdx.z;
    int i = threadIdx.x >> 5, j = threadIdx.x & 31;
    #pragma unroll
    for (int p = 0; p < 4; p++) {
        int t = t0 + i + p * 8;
        tile[i + p * 8][j] = (t < 196) ? hnb[((long)b * 196 + t) * 768 + d0 + j] : (u16)0;
    }
    __syncthreads();
    #pragma unroll
    for (int p = 0; p < 4; p++) {
        int dd = i + p * 8;
        hnT[((long)b * 768 + d0 + dd) * 224 + t0 + j] = tile[j][dd];
    }
}

// hnb = LN(hnb + LN(sum of 4 split-K partials))  [in-place: reads first]
__global__ __launch_bounds__(256) void k_final_h(const float* __restrict__ rawK,
                                                 u16* __restrict__ hnb) {
    __shared__ float sm[4];
    const long PS = (long)MC * 768;
    int r = blockIdx.x, tid = threadIdx.x;
    const float* rp = rawK + (long)r * 768;
    u16* hp = hnb + (long)r * 768;
    float y0 = rp[tid] + rp[tid + PS] + rp[tid + 2 * PS] + rp[tid + 3 * PS];
    float y1 = rp[tid + 256] + rp[tid + 256 + PS] + rp[tid + 256 + 2 * PS] + rp[tid + 256 + 3 * PS];
    float y2 = rp[tid + 512] + rp[tid + 512 + PS] + rp[tid + 512 + 2 * PS] + rp[tid + 512 + 3 * PS];
    float h0 = bf2f(hp[tid]), h1 = bf2f(hp[tid + 256]), h2 = bf2f(hp[tid + 512]);
    float mean = block_reduce_sum(y0 + y1 + y2, sm) * (1.f / 768.f);
    float d0 = y0 - mean, d1 = y1 - mean, d2 = y2 - mean;
    float var = block_reduce_sum(d0 * d0 + d1 * d1 + d2 * d2, sm) * (1.f / 768.f);
    float rs = rsqrtf(var + LN_EPS);
    float s0 = h0 + d0 * rs;
    float s1 = h1 + d1 * rs;
    float s2 = h2 + d2 * rs;
    mean = block_reduce_sum(s0 + s1 + s2, sm) * (1.f / 768.f);
    d0 = s0 - mean; d1 = s1 - mean; d2 = s2 - mean;
    var = block_reduce_sum(d0 * d0 + d1 * d1 + d2 * d2, sm) * (1.f / 768.f);
    rs = rsqrtf(var + LN_EPS);
    hp[tid] = f2bf(d0 * rs);
    hp[tid + 256] = f2bf(d1 * rs);
    hp[tid + 512] = f2bf(d2 * rs);
}

// pool stage 1: partial sums over 14-row groups -> part[b][g][768] (bf16 in)
__global__ __launch_bounds__(256) void k_pool1(const u16* __restrict__ hnb,
                                               float* __restrict__ part) {
    int g = blockIdx.x, b = blockIdx.y, tid = threadIdx.x;
    const u16* base = hnb + ((long)b * 196 + g * 14) * 768;
    float a0 = 0.f, a1 = 0.f, a2 = 0.f;
    for (int t = 0; t < 14; t++) {
        const u16* p = base + (long)t * 768;
        a0 += bf2f(p[tid]); a1 += bf2f(p[tid + 256]); a2 += bf2f(p[tid + 512]);
    }
    float* pp = part + ((long)b * 14 + g) * 768;
    pp[tid] = a0; pp[tid + 256] = a1; pp[tid + 512] = a2;
}

// pool stage 2: pooled = LN(sum(part)/196)
__global__ __launch_bounds__(256) void k_pool2(const float* __restrict__ part,
                                               float* __restrict__ pooled) {
    __shared__ float sm[4];
    int b = blockIdx.x, tid = threadIdx.x;
    const float* pp = part + (long)b * 14 * 768;
    float a0 = 0.f, a1 = 0.f, a2 = 0.f;
    for (int g = 0; g < 14; g++) {
        a0 += pp[g * 768 + tid]; a1 += pp[g * 768 + tid + 256]; a2 += pp[g * 768 + tid + 512];
    }
    a0 *= (1.f / 196.f); a1 *= (1.f / 196.f); a2 *= (1.f / 196.f);
    float mean = block_reduce_sum(a0 + a1 + a2, sm) * (1.f / 768.f);
    float d0 = a0 - mean, d1 = a1 - mean, d2 = a2 - mean;
    float var = block_reduce_sum(d0 * d0 + d1 * d1 + d2 * d2, sm) * (1.f / 768.f);
    float rs = rsqrtf(var + LN_EPS);
    pooled[(long)b * 768 + tid] = d0 * rs;
    pooled[(long)b * 768 + tid + 256] = d1 * rs;
    pooled[(long)b * 768 + tid + 512] = d2 * rs;
}

// out = pooled @ head_w^T + head_b.  grid (250, 64): wave w -> col 4*bx+w.
__global__ __launch_bounds__(256) void k_head(const float* __restrict__ pooled,
                                              const float* __restrict__ hw,
                                              const float* __restrict__ hb,
                                              float* __restrict__ out) {
    __shared__ float pr[768];
    int b = blockIdx.y, tid = threadIdx.x;
    pr[tid] = pooled[(long)b * 768 + tid];
    pr[tid + 256] = pooled[(long)b * 768 + tid + 256];
    pr[tid + 512] = pooled[(long)b * 768 + tid + 512];
    __syncthreads();
    int c = blockIdx.x * 4 + (tid >> 6);
    int lane = tid & 63;
    const float* wrow = hw + (long)c * 768;
    float acc = 0.f;
    #pragma unroll
    for (int k = 0; k < 768; k += 64) acc += pr[k + lane] * wrow[k + lane];
    #pragma unroll
    for (int o = 32; o; o >>= 1) acc += __shfl_xor(acc, o);
    if (lane == 0) out[(long)b * 1000 + c] = acc + hb[c];
}

// ---------------------------------------------------------------------------
extern "C" void kernel_launch(void* const* d_in, const int* in_sizes, int n_in,
                              void* d_out, int out_size, void* d_ws, size_t ws_size,
                              hipStream_t stream) {
    const float* x     = (const float*)d_in[0];
    const float* convw = (const float*)d_in[1];
    const float* convb = (const float*)d_in[2];
    const float* pe    = (const float*)d_in[3];
    const float* enc   = (const float*)d_in[4];
    const float* encv  = (const float*)d_in[5];
    const float* dec   = (const float*)d_in[6];
    const float* freqs = (const float*)d_in[7];
    const float* hw    = (const float*)d_in[8];
    const float* hbias = (const float*)d_in[9];
    float* out = (float*)d_out;

    char* W = (char*)d_ws;
    size_t off = 0;
    auto ALLOC = [&](size_t bytes) {
        size_t o = off;
        off += (bytes + 255) & ~(size_t)255;
        return o;
    };
    // persistent
    float* bh    = (float*)(W + ALLOC(38535168));            // h f32 (setup only)
    u16*   bhnb  = (u16*)  (W + ALLOC(19267584 + 524288));   // hn bf16 (+edge slack)
    u16*   bhnT  = (u16*)  (W + ALLOC(22020096));            // hn^T bf16 (64,768,224)
    u16*   benc  = (u16*)  (W + ALLOC(9437184));             // enc^T  (12,512,768)
    u16*   bencv = (u16*)  (W + ALLOC(9437184));             // encv^T
    u16*   bdec  = (u16*)  (W + ALLOC(9437184));             // dec^T  (768,6144)
    float* btc   = (float*)(W + ALLOC(401408));              // cos (196,512)
    float* bts   = (float*)(W + ALLOC(401408));              // sin
    float* bpool = (float*)(W + ALLOC(196608));              // pooled (64,768)
    float* bpart = (float*)(W + ALLOC(2752512));             // pool partials (64,14,768)
    float* bstats= (float*)(W + ALLOC(301056));              // ykv row stats (192*196 x f32x2)
    float* bcs   = (float*)(W + ALLOC(24576));               // encv colsums (12,512)
    // chunk regions (+slack for masked edge-tile overreads)
    char*  R1    = (char*) (W + ALLOC(38535168 + 2097152));  // qr / z
    char*  R2    = (char*) (W + ALLOC(57802752 + 524288));   // ykv / rawK (+setup patches)
    char*  R3    = (char*) (W + ALLOC(38535168 + 524288));   // xs (+setup conv_w)
    (void)ws_size; (void)in_sizes; (void)n_in; (void)out_size;

    u16*   bap  = (u16*)R2;    // setup: packed patches (18.4M)
    u16*   bcw  = (u16*)R3;    // setup: conv_w bf16 (1.2M)
    u16*   qr   = (u16*)R1;    // per-chunk head-major (192hb,196,512)
    u16*   z    = (u16*)R1;    // (3136,6144)
    u16*   ykv  = (u16*)R2;    // head-major (192hb,196,768)
    float* rawK = (float*)R2;  // yMLP split-K partials 4x(3136,768) f32
    u16*   xs   = (u16*)R3;    // head-major (192hb,196,512)

    // ---- setup ----
    k_pack_patches<<<37632, 256, 0, stream>>>(x, bap);
    k_cast<<<2304, 256, 0, stream>>>(convw, bcw, 768 * 768);
    k_gemm_tokens<<<dim3(98, 6), 256, 0, stream>>>(bap, bcw, convb, pe, bh);
    k_transpose_cast<<<dim3(16, 24, 12), 256, 0, stream>>>(enc, benc, 768, 512);
    k_transpose_cast<<<dim3(16, 24, 12), 256, 0, stream>>>(encv, bencv, 768, 512);
    k_transpose_cast<<<dim3(24, 192, 1), 256, 0, stream>>>(dec, bdec, 6144, 768);
    k_rope_tab<<<392, 256, 0, stream>>>(freqs, btc, bts);
    k_colsum<<<dim3(2, 12), 256, 0, stream>>>(encv, bcs);
    k_ln1<<<12544, 256, 0, stream>>>(bh, bhnb);   // once; thereafter LN(LN)~id

    // ---- 6 shared-weight layers, 4 chunks of 16 images each ----
    for (int L = 0; L < 6; ++L) {
        k_hnT<<<dim3(7, 24, 64), 256, 0, stream>>>(bhnb, bhnT);
        for (int c = 0; c < 4; ++c) {
            long r0 = (long)c * MC;                    // chunk row offset
            k_gemm_xs<<<dim3(25, 48), 256, 0, stream>>>(
                bhnb + r0 * 768, benc, btc, bts, xs, qr);
            k_attn<<<384, 256, 0, stream>>>(
                qr, bhnT + (long)c * 16 * 768 * 224, ykv, bstats);
            k_gemm_ys<<<dim3(25, 4, 12), 256, 0, stream>>>(ykv, bencv, xs, bstats, bcs, z);
            k_gemm_mlp<<<dim3(25, 6, 4), 256, 0, stream>>>(z, bdec, rawK);
            k_final_h<<<MC, 256, 0, stream>>>(rawK, bhnb + r0 * 768);
        }
    }

    // ---- head ----
    k_pool1<<<dim3(14, 64), 256, 0, stream>>>(bhnb, bpart);
    k_pool2<<<64, 256, 0, stream>>>(bpart, bpool);
    k_head<<<dim3(250, 64), 256, 0, stream>>>(bpool, hw, hbias, out);
}